// Round 1
// baseline (500.658 us; speedup 1.0000x reference)
//
#include <hip/hip_runtime.h>
#include <math.h>

typedef unsigned int u32;
typedef unsigned long long u64;

#define BB 16
#define NANCH 17064
#define NTOP 1000
#define NWORD 16
#define NOUT 100
#define NBIN 8192

// ---------------------------------------------------------------- kernel A
__global__ void k_anchor(const float* __restrict__ c0, const float* __restrict__ c1,
                         const float* __restrict__ c2, const float* __restrict__ c3,
                         const float* __restrict__ c4,
                         const float* __restrict__ r0, const float* __restrict__ r1,
                         const float* __restrict__ r2, const float* __restrict__ r3,
                         const float* __restrict__ r4,
                         u32* __restrict__ akey, float* __restrict__ ascore,
                         int* __restrict__ aclass, float* __restrict__ abox) {
    int a = blockIdx.x * blockDim.x + threadIdx.x;
    int b = blockIdx.y;
    if (a >= NANCH) return;
    const float *cp, *rp;
    int loc, wl, h, stride, half;
    if (a < 12800)      { loc = a;         wl = 7; h = 100; stride = 8;   half = 4;  cp = c0; rp = r0; }
    else if (a < 16000) { loc = a - 12800; wl = 6; h = 50;  stride = 16;  half = 8;  cp = c1; rp = r1; }
    else if (a < 16800) { loc = a - 16000; wl = 5; h = 25;  stride = 32;  half = 16; cp = c2; rp = r2; }
    else if (a < 17008) { loc = a - 16800; wl = 4; h = 13;  stride = 64;  half = 32; cp = c3; rp = r3; }
    else                { loc = a - 17008; wl = 3; h = 7;   stride = 128; half = 64; cp = c4; rp = r4; }
    int y = loc >> wl, x = loc & ((1 << wl) - 1);
    int hw = h << wl;
    const float* cbase = cp + (size_t)b * 80 * hw + loc;
    float m = cbase[0];
    int arg = 0;
    for (int c = 1; c < 80; ++c) {
        float v = cbase[(size_t)c * hw];
        if (v > m) { m = v; arg = c; }   // first-max tiebreak == jnp.argmax
    }
    const float* rbase = rp + (size_t)b * 4 * hw + loc;
    float g0 = rbase[0], g1 = rbase[hw], g2 = rbase[2 * hw], g3 = rbase[3 * hw];
    float cx = (float)(x * stride + half), cy = (float)(y * stride + half);
    int idx = b * NANCH + a;
    u32 kb = __float_as_uint(m);
    kb = (kb & 0x80000000u) ? ~kb : (kb | 0x80000000u);  // monotone float->uint
    akey[idx] = kb;
    ascore[idx] = 1.0f / (1.0f + expf(-m));
    aclass[idx] = arg + 1;
    abox[idx * 4 + 0] = cx - g0;
    abox[idx * 4 + 1] = cy - g1;
    abox[idx * 4 + 2] = cx + g2;
    abox[idx * 4 + 3] = cy + g3;
}

// ---------------------------------------------------------------- kernel B
__global__ void k_hist(const u32* __restrict__ akey, u32* __restrict__ Tbin,
                       u32* __restrict__ ccnt) {
    __shared__ u32 hist[NBIN];
    __shared__ u32 seg[256];
    int b = blockIdx.x, t = threadIdx.x;
    for (int i = t; i < NBIN; i += 256) hist[i] = 0;
    __syncthreads();
    const u32* ak = akey + b * NANCH;
    for (int i = t; i < NANCH; i += 256) atomicAdd(&hist[ak[i] >> 19], 1u);
    __syncthreads();
    u32 s = 0;
    for (int i = 0; i < 32; ++i) s += hist[t * 32 + i];
    seg[t] = s;
    __syncthreads();
    if (t == 0) {
        u32 acc = 0;
        int Tv = 0;
        for (int g = 255; g >= 0; --g) {
            if (acc + seg[g] >= NTOP) {
                for (int bin = g * 32 + 31; bin >= g * 32; --bin) {
                    acc += hist[bin];
                    if (acc >= NTOP) { Tv = bin; break; }
                }
                break;
            }
            acc += seg[g];
        }
        Tbin[b] = (u32)Tv;
        ccnt[b] = 0;
    }
}

// ---------------------------------------------------------------- kernel C
__global__ void k_compact(const u32* __restrict__ akey, const u32* __restrict__ Tbin,
                          u32* __restrict__ ccnt, u64* __restrict__ cand) {
    int a = blockIdx.x * blockDim.x + threadIdx.x;
    int b = blockIdx.y;
    if (a >= NANCH) return;
    u32 k = akey[b * NANCH + a];
    if ((k >> 19) >= Tbin[b]) {
        u32 p = atomicAdd(&ccnt[b], 1u);
        cand[b * NANCH + p] = ((u64)k << 32) | (u64)(0xFFFFFFFFu - (u32)a);
    }
}

// ---------------------------------------------------------------- kernel D
__global__ void k_rank(const u64* __restrict__ cand, const u32* __restrict__ ccnt,
                       const float* __restrict__ ascore, const int* __restrict__ aclass,
                       const float* __restrict__ abox,
                       float* __restrict__ tscore, int* __restrict__ tclass,
                       float* __restrict__ tbox) {
    __shared__ u64 tile[1024];
    int b = blockIdx.y, tid = threadIdx.x;
    int C = (int)ccnt[b];
    const u64* ck = cand + b * NANCH;
    for (int base = blockIdx.x * 256; base < C; base += gridDim.x * 256) {
        int i = base + tid;
        bool have = i < C;
        u64 my = have ? ck[i] : 0ull;
        int rank = 0;
        for (int t0 = 0; t0 < C; t0 += 1024) {
            int nt = min(1024, C - t0);
            __syncthreads();
            for (int j = tid; j < nt; j += 256) tile[j] = ck[t0 + j];
            __syncthreads();
            if (have)
                for (int j = 0; j < nt; ++j) rank += (tile[j] > my) ? 1 : 0;
        }
        if (have && rank < NTOP) {
            u32 a = 0xFFFFFFFFu - (u32)(my & 0xFFFFFFFFull);
            int src = b * NANCH + (int)a;
            int dst = b * NTOP + rank;
            tscore[dst] = ascore[src];
            tclass[dst] = aclass[src];
            tbox[dst * 4 + 0] = abox[src * 4 + 0];
            tbox[dst * 4 + 1] = abox[src * 4 + 1];
            tbox[dst * 4 + 2] = abox[src * 4 + 2];
            tbox[dst * 4 + 3] = abox[src * 4 + 3];
        }
    }
}

// ---------------------------------------------------------------- kernel E
__global__ void k_maxc(const float* __restrict__ tscore, const float* __restrict__ tbox,
                       float* __restrict__ maxc) {
    __shared__ float red[256];
    int b = blockIdx.x, t = threadIdx.x;
    float m = -3.0e38f;
    for (int i = t; i < NTOP; i += 256) {
        if (tscore[b * NTOP + i] >= 0.05f) {
            const float* bx = tbox + (size_t)(b * NTOP + i) * 4;
            m = fmaxf(m, fmaxf(fmaxf(bx[0], bx[1]), fmaxf(bx[2], bx[3])));
        }
    }
    red[t] = m;
    __syncthreads();
    for (int s = 128; s > 0; s >>= 1) {
        if (t < s) red[t] = fmaxf(red[t], red[t + s]);
        __syncthreads();
    }
    if (t == 0) maxc[b] = red[0];
}

// ---------------------------------------------------------------- kernel F
__global__ void k_sup(const float* __restrict__ tbox, const int* __restrict__ tclass,
                      const float* __restrict__ maxc, u64* __restrict__ sup) {
    int tj = blockIdx.x, ti = blockIdx.y, b = blockIdx.z;
    int t = threadIdx.x;
    __shared__ double jx1[64], jy1[64], jx2[64], jy2[64], jcx[64], jcy[64], jar[64];
    double mc1 = (double)maxc[b] + 1.0;
    int j = tj * 64 + t;
    if (j < NTOP) {
        const float* bx = tbox + (size_t)(b * NTOP + j) * 4;
        double o = (double)tclass[b * NTOP + j] * mc1;
        double x1 = (double)bx[0] + o, y1 = (double)bx[1] + o;
        double x2 = (double)bx[2] + o, y2 = (double)bx[3] + o;
        jx1[t] = x1; jy1[t] = y1; jx2[t] = x2; jy2[t] = y2;
        jcx[t] = (x1 + x2) * 0.5; jcy[t] = (y1 + y2) * 0.5;
        jar[t] = (x2 - x1 + 1.0) * (y2 - y1 + 1.0);
    }
    __syncthreads();
    int i = ti * 64 + t;
    if (i >= NTOP) return;
    const float* bx = tbox + (size_t)(b * NTOP + i) * 4;
    double o = (double)tclass[b * NTOP + i] * mc1;
    double ix1 = (double)bx[0] + o, iy1 = (double)bx[1] + o;
    double ix2 = (double)bx[2] + o, iy2 = (double)bx[3] + o;
    double icx = (ix1 + ix2) * 0.5, icy = (iy1 + iy2) * 0.5;
    double iar = (ix2 - ix1 + 1.0) * (iy2 - iy1 + 1.0);
    u64 bits = 0;
    int jbase = tj * 64;
    for (int jj = 0; jj < 64; ++jj) {
        int jg = jbase + jj;
        if (jg >= NTOP) break;
        if (jg <= i) continue;
        double xm = fmax(ix1, jx1[jj]), ym = fmax(iy1, jy1[jj]);
        double xM = fmin(ix2, jx2[jj]), yM = fmin(iy2, jy2[jj]);
        double inter = fmax(xM - xm, 0.0) * fmax(yM - ym, 0.0);
        double iou = inter / (iar + jar[jj] - inter);
        double dx = icx - jcx[jj], dy = icy - jcy[jj];
        double idg = dx * dx + dy * dy;
        double ox = fmax(ix2, jx2[jj]) - fmin(ix1, jx1[jj]);
        double oy = fmax(iy2, jy2[jj]) - fmin(iy1, jy1[jj]);
        double odg = ox * ox + oy * oy;
        double diou = iou - idg / fmax(odg, 1e-12);
        if (diou > 0.6) bits |= (1ull << jj);
    }
    sup[(size_t)(b * NTOP + i) * NWORD + tj] = bits;
}

// ---------------------------------------------------------------- kernel G
__global__ void k_scan(const u64* __restrict__ sup, const float* __restrict__ tscore,
                       const int* __restrict__ tclass, const float* __restrict__ tbox,
                       float* __restrict__ out) {
    int b = blockIdx.x, lane = threadIdx.x;
    __shared__ u64 chunk[1024];
    u64 validw = 0;
    if (lane < NWORD) {
        for (int k = 0; k < 64; ++k) {
            int i = lane * 64 + k;
            if (i < NTOP && tscore[b * NTOP + i] >= 0.05f) validw |= (1ull << k);
        }
    }
    u64 remv = 0;
    const u64* supb = sup + (size_t)b * NTOP * NWORD;
    for (int ch = 0; ch < NWORD; ++ch) {
        __syncthreads();
        for (int idx = lane; idx < 1024; idx += 64) {
            int r = ch * 64 + (idx >> 4);
            chunk[idx] = (r < NTOP) ? supb[ch * 1024 + idx] : 0ull;
        }
        __syncthreads();
        int nr = min(64, NTOP - ch * 64);
        for (int k = 0; k < nr; ++k) {
            u64 rv = __shfl(remv, ch);
            u64 vv = __shfl(validw, ch);
            bool keep = (((vv >> k) & 1ull) != 0ull) && (((rv >> k) & 1ull) == 0ull);
            if (keep && lane < NWORD) remv |= chunk[(k << 4) + lane];
        }
    }
    u64 keepw = (lane < NWORD) ? (validw & ~remv) : 0ull;
    float* os = out + b * NOUT;
    float* oc = out + BB * NOUT + b * NOUT;
    float* ob = out + 2 * BB * NOUT + (size_t)b * NOUT * 4;
    for (int i = lane; i < NOUT; i += 64) os[i] = -2.0f;
    for (int i = lane; i < NOUT; i += 64) oc[i] = -2.0f;
    for (int i = lane; i < NOUT * 4; i += 64) ob[i] = -2.0f;
    __syncthreads();
    int cnt = __popcll(keepw);
    int pre = cnt;
    for (int off = 1; off < 64; off <<= 1) {
        int n = __shfl_up(pre, off);
        if (lane >= off) pre += n;
    }
    pre -= cnt;  // exclusive prefix of kept counts
    if (lane < NWORD) {
        int rank = pre;
        for (int k = 0; k < 64 && rank < NOUT; ++k) {
            if ((keepw >> k) & 1ull) {
                int i = lane * 64 + k;
                os[rank] = tscore[b * NTOP + i];
                oc[rank] = (float)tclass[b * NTOP + i];
                ob[rank * 4 + 0] = tbox[(size_t)(b * NTOP + i) * 4 + 0];
                ob[rank * 4 + 1] = tbox[(size_t)(b * NTOP + i) * 4 + 1];
                ob[rank * 4 + 2] = tbox[(size_t)(b * NTOP + i) * 4 + 2];
                ob[rank * 4 + 3] = tbox[(size_t)(b * NTOP + i) * 4 + 3];
                rank++;
            }
        }
    }
}

// ---------------------------------------------------------------- launch
extern "C" void kernel_launch(void* const* d_in, const int* in_sizes, int n_in,
                              void* d_out, int out_size, void* d_ws, size_t ws_size,
                              hipStream_t stream) {
    (void)in_sizes; (void)n_in; (void)out_size; (void)ws_size;
    // setup_inputs dict order is interleaved: cls0,reg0,cls1,reg1,...,cls4,reg4
    const float* cls[5];
    const float* reg[5];
    for (int i = 0; i < 5; ++i) {
        cls[i] = (const float*)d_in[2 * i];
        reg[i] = (const float*)d_in[2 * i + 1];
    }
    float* out = (float*)d_out;

    char* ws = (char*)d_ws;
    u64* cand = (u64*)ws;            ws += (size_t)BB * NANCH * sizeof(u64);
    u64* sup = (u64*)ws;             ws += (size_t)BB * NTOP * NWORD * sizeof(u64);
    u32* akey = (u32*)ws;            ws += (size_t)BB * NANCH * sizeof(u32);
    float* ascore = (float*)ws;      ws += (size_t)BB * NANCH * sizeof(float);
    int* aclass = (int*)ws;          ws += (size_t)BB * NANCH * sizeof(int);
    float* abox = (float*)ws;        ws += (size_t)BB * NANCH * 4 * sizeof(float);
    float* tscore = (float*)ws;      ws += (size_t)BB * NTOP * sizeof(float);
    int* tclass = (int*)ws;          ws += (size_t)BB * NTOP * sizeof(int);
    float* tbox = (float*)ws;        ws += (size_t)BB * NTOP * 4 * sizeof(float);
    u32* Tbin = (u32*)ws;            ws += 64;
    u32* ccnt = (u32*)ws;            ws += 64;
    float* maxc = (float*)ws;        ws += 64;

    dim3 gA((NANCH + 255) / 256, BB);
    k_anchor<<<gA, 256, 0, stream>>>(cls[0], cls[1], cls[2], cls[3], cls[4],
                                     reg[0], reg[1], reg[2], reg[3], reg[4],
                                     akey, ascore, aclass, abox);
    k_hist<<<BB, 256, 0, stream>>>(akey, Tbin, ccnt);
    k_compact<<<gA, 256, 0, stream>>>(akey, Tbin, ccnt, cand);
    k_rank<<<dim3(32, BB), 256, 0, stream>>>(cand, ccnt, ascore, aclass, abox,
                                             tscore, tclass, tbox);
    k_maxc<<<BB, 256, 0, stream>>>(tscore, tbox, maxc);
    k_sup<<<dim3(16, 16, BB), 64, 0, stream>>>(tbox, tclass, maxc, sup);
    k_scan<<<BB, 64, 0, stream>>>(sup, tscore, tclass, tbox, out);
}

// Round 2
// 415.574 us; speedup vs baseline: 1.2047x; 1.2047x over previous
//
#include <hip/hip_runtime.h>
#include <math.h>

typedef unsigned int u32;
typedef unsigned long long u64;

#define BB 16
#define NANCH 17064
#define NTOP 1000
#define NWORD 16
#define NOUT 100
#define NBIN 8192

__device__ __forceinline__ u32 fmap(float v) {
    u32 u = __float_as_uint(v);
    return (u & 0x80000000u) ? ~u : (u | 0x80000000u);
}
__device__ __forceinline__ float funmap(u32 u) {
    u32 b = (u & 0x80000000u) ? (u & 0x7FFFFFFFu) : ~u;
    return __uint_as_float(b);
}

// ---------------------------------------------------------------- kernel A
__global__ void k_anchor(const float* __restrict__ c0, const float* __restrict__ c1,
                         const float* __restrict__ c2, const float* __restrict__ c3,
                         const float* __restrict__ c4,
                         const float* __restrict__ r0, const float* __restrict__ r1,
                         const float* __restrict__ r2, const float* __restrict__ r3,
                         const float* __restrict__ r4,
                         u32* __restrict__ akey, float* __restrict__ ascore,
                         int* __restrict__ aclass, float* __restrict__ abox,
                         u32* __restrict__ ghist) {
    int a = blockIdx.x * blockDim.x + threadIdx.x;
    int b = blockIdx.y;
    if (a >= NANCH) return;
    const float *cp, *rp;
    int loc, wl, h, stride, half;
    if (a < 12800)      { loc = a;         wl = 7; h = 100; stride = 8;   half = 4;  cp = c0; rp = r0; }
    else if (a < 16000) { loc = a - 12800; wl = 6; h = 50;  stride = 16;  half = 8;  cp = c1; rp = r1; }
    else if (a < 16800) { loc = a - 16000; wl = 5; h = 25;  stride = 32;  half = 16; cp = c2; rp = r2; }
    else if (a < 17008) { loc = a - 16800; wl = 4; h = 13;  stride = 64;  half = 32; cp = c3; rp = r3; }
    else                { loc = a - 17008; wl = 3; h = 7;   stride = 128; half = 64; cp = c4; rp = r4; }
    int y = loc >> wl, x = loc & ((1 << wl) - 1);
    int hw = h << wl;
    const float* cbase = cp + (size_t)b * 80 * hw + loc;
    float m = cbase[0];
    int arg = 0;
#pragma unroll 8
    for (int c = 1; c < 80; ++c) {
        float v = cbase[(size_t)c * hw];
        if (v > m) { m = v; arg = c; }   // first-max tiebreak == jnp.argmax
    }
    const float* rbase = rp + (size_t)b * 4 * hw + loc;
    float g0 = rbase[0], g1 = rbase[hw], g2 = rbase[2 * hw], g3 = rbase[3 * hw];
    float cx = (float)(x * stride + half), cy = (float)(y * stride + half);
    int idx = b * NANCH + a;
    u32 kb = fmap(m);                     // monotone float->uint sort key
    akey[idx] = kb;
    ascore[idx] = 1.0f / (1.0f + expf(-m));
    aclass[idx] = arg + 1;
    abox[idx * 4 + 0] = cx - g0;
    abox[idx * 4 + 1] = cy - g1;
    abox[idx * 4 + 2] = cx + g2;
    abox[idx * 4 + 3] = cy + g3;
    atomicAdd(&ghist[b * NBIN + (kb >> 19)], 1u);
}

// ---------------------------------------------------------------- kernel B
__global__ void k_thresh(const u32* __restrict__ ghist, u32* __restrict__ Tbin) {
    __shared__ u32 seg[256];
    int b = blockIdx.x, t = threadIdx.x;
    const u32* h = ghist + b * NBIN;
    u32 s = 0;
    for (int i = 0; i < 32; ++i) s += h[t * 32 + i];
    seg[t] = s;
    __syncthreads();
    if (t == 0) {
        u32 acc = 0;
        int Tv = 0;
        for (int g = 255; g >= 0; --g) {
            if (acc + seg[g] >= NTOP) {
                for (int bin = g * 32 + 31; bin >= g * 32; --bin) {
                    acc += h[bin];
                    if (acc >= NTOP) { Tv = bin; break; }
                }
                break;
            }
            acc += seg[g];
        }
        Tbin[b] = (u32)Tv;
    }
}

// ---------------------------------------------------------------- kernel C
__global__ void k_compact(const u32* __restrict__ akey, const u32* __restrict__ Tbin,
                          u32* __restrict__ ccnt, u64* __restrict__ cand) {
    int a = blockIdx.x * blockDim.x + threadIdx.x;
    int b = blockIdx.y;
    if (a >= NANCH) return;
    u32 k = akey[b * NANCH + a];
    if ((k >> 19) >= Tbin[b]) {
        u32 p = atomicAdd(&ccnt[b], 1u);
        cand[b * NANCH + p] = ((u64)k << 32) | (u64)(0xFFFFFFFFu - (u32)a);
    }
}

// ---------------------------------------------------------------- kernel D
__global__ void k_rank(const u64* __restrict__ cand, const u32* __restrict__ ccnt,
                       const float* __restrict__ ascore, const int* __restrict__ aclass,
                       const float* __restrict__ abox,
                       float* __restrict__ tscore, int* __restrict__ tclass,
                       float* __restrict__ tbox, u32* __restrict__ maxcU) {
    __shared__ u64 tile[1024];
    int b = blockIdx.y, tid = threadIdx.x;
    int C = (int)ccnt[b];
    const u64* ck = cand + b * NANCH;
    for (int base = blockIdx.x * 256; base < C; base += gridDim.x * 256) {
        int i = base + tid;
        bool have = i < C;
        u64 my = have ? ck[i] : 0ull;
        int rank = 0;
        for (int t0 = 0; t0 < C; t0 += 1024) {
            int nt = min(1024, C - t0);
            __syncthreads();
            for (int j = tid; j < nt; j += 256) tile[j] = ck[t0 + j];
            __syncthreads();
            if (have)
                for (int j = 0; j < nt; ++j) rank += (tile[j] > my) ? 1 : 0;
        }
        u32 mymax = 0;  // identity: maps below any finite float's code
        if (have && rank < NTOP) {
            u32 a = 0xFFFFFFFFu - (u32)(my & 0xFFFFFFFFull);
            int src = b * NANCH + (int)a;
            int dst = b * NTOP + rank;
            float sc = ascore[src];
            float b0 = abox[src * 4 + 0], b1 = abox[src * 4 + 1];
            float b2 = abox[src * 4 + 2], b3 = abox[src * 4 + 3];
            tscore[dst] = sc;
            tclass[dst] = aclass[src];
            tbox[dst * 4 + 0] = b0;
            tbox[dst * 4 + 1] = b1;
            tbox[dst * 4 + 2] = b2;
            tbox[dst * 4 + 3] = b3;
            if (sc >= 0.05f)
                mymax = fmap(fmaxf(fmaxf(b0, b1), fmaxf(b2, b3)));
        }
        for (int off = 32; off > 0; off >>= 1) {
            u32 o = (u32)__shfl_down((int)mymax, off);
            mymax = mymax > o ? mymax : o;
        }
        if ((tid & 63) == 0) atomicMax(&maxcU[b], mymax);
    }
}

// ---------------------------------------------------------------- kernel F
__global__ void k_sup(const float* __restrict__ tbox, const int* __restrict__ tclass,
                      const u32* __restrict__ maxcU, u64* __restrict__ sup) {
    int tj = blockIdx.x, ti = blockIdx.y, b = blockIdx.z;
    int t = threadIdx.x;
    __shared__ double jx1[64], jy1[64], jx2[64], jy2[64], jcx[64], jcy[64], jar[64];
    double mc1 = (double)funmap(maxcU[b]) + 1.0;
    int j = tj * 64 + t;
    if (j < NTOP) {
        const float* bx = tbox + (size_t)(b * NTOP + j) * 4;
        double o = (double)tclass[b * NTOP + j] * mc1;
        double x1 = (double)bx[0] + o, y1 = (double)bx[1] + o;
        double x2 = (double)bx[2] + o, y2 = (double)bx[3] + o;
        jx1[t] = x1; jy1[t] = y1; jx2[t] = x2; jy2[t] = y2;
        jcx[t] = (x1 + x2) * 0.5; jcy[t] = (y1 + y2) * 0.5;
        jar[t] = (x2 - x1 + 1.0) * (y2 - y1 + 1.0);
    }
    __syncthreads();
    int i = ti * 64 + t;
    if (i >= NTOP) return;
    const float* bx = tbox + (size_t)(b * NTOP + i) * 4;
    double o = (double)tclass[b * NTOP + i] * mc1;
    double ix1 = (double)bx[0] + o, iy1 = (double)bx[1] + o;
    double ix2 = (double)bx[2] + o, iy2 = (double)bx[3] + o;
    double icx = (ix1 + ix2) * 0.5, icy = (iy1 + iy2) * 0.5;
    double iar = (ix2 - ix1 + 1.0) * (iy2 - iy1 + 1.0);
    u64 bits = 0;
    int jbase = tj * 64;
    for (int jj = 0; jj < 64; ++jj) {
        int jg = jbase + jj;
        if (jg >= NTOP) break;
        if (jg <= i) continue;
        double xm = fmax(ix1, jx1[jj]), ym = fmax(iy1, jy1[jj]);
        double xM = fmin(ix2, jx2[jj]), yM = fmin(iy2, jy2[jj]);
        double inter = fmax(xM - xm, 0.0) * fmax(yM - ym, 0.0);
        double iou = inter / (iar + jar[jj] - inter);
        double dx = icx - jcx[jj], dy = icy - jcy[jj];
        double idg = dx * dx + dy * dy;
        double ox = fmax(ix2, jx2[jj]) - fmin(ix1, jx1[jj]);
        double oy = fmax(iy2, jy2[jj]) - fmin(iy1, jy1[jj]);
        double odg = ox * ox + oy * oy;
        double diou = iou - idg / fmax(odg, 1e-12);
        if (diou > 0.6) bits |= (1ull << jj);
    }
    sup[(size_t)(b * NTOP + i) * NWORD + tj] = bits;
}

// ---------------------------------------------------------------- kernel G
__global__ void k_scan(const u64* __restrict__ sup, const float* __restrict__ tscore,
                       const int* __restrict__ tclass, const float* __restrict__ tbox,
                       float* __restrict__ out) {
    int b = blockIdx.x, lane = threadIdx.x;  // 64 threads
    __shared__ u64 rows[64 * NWORD];         // one 64-row tile of sup (8 KB)
    __shared__ int kept_idx[NOUT];
    u64 remv[NWORD], valid[NWORD];
#pragma unroll
    for (int w = 0; w < NWORD; ++w) remv[w] = 0;
#pragma unroll
    for (int t = 0; t < NWORD; ++t) {
        int i = t * 64 + lane;
        float s = (i < NTOP) ? tscore[b * NTOP + i] : -1.0f;
        valid[t] = __ballot(s >= 0.05f);   // uniform across wave
    }
    const u64* supb = sup + (size_t)b * NTOP * NWORD;
    int kept = 0;
    for (int t = 0; t < NWORD && kept < NOUT; ++t) {
        __syncthreads();
        for (int q = 0; q < NWORD; ++q) {
            int idx = q * 64 + lane;                 // idx = r*16 + w within tile
            int r = t * 64 + (idx >> 4);
            rows[idx] = (r < NTOP) ? supb[(size_t)t * 1024 + idx] : 0ull;
        }
        __syncthreads();
        int nr = min(64, NTOP - t * 64);
        for (int k = 0; k < nr; ++k) {
            bool keep = (((valid[t] >> k) & 1ull) != 0ull) &&
                        (((remv[t] >> k) & 1ull) == 0ull);
            if (keep) {                               // wave-uniform branch
#pragma unroll
                for (int w = 0; w < NWORD; ++w) remv[w] |= rows[k * NWORD + w];
                if (lane == 0) kept_idx[kept] = t * 64 + k;
                ++kept;
                if (kept >= NOUT) break;
            }
        }
    }
    __syncthreads();
    float* os = out + b * NOUT;
    float* oc = out + BB * NOUT + b * NOUT;
    float* ob = out + 2 * BB * NOUT + (size_t)b * NOUT * 4;
    for (int i = lane; i < NOUT; i += 64) { os[i] = -2.0f; oc[i] = -2.0f; }
    for (int i = lane; i < NOUT * 4; i += 64) ob[i] = -2.0f;
    __syncthreads();
    int ncopy = kept < NOUT ? kept : NOUT;
    for (int r = lane; r < ncopy; r += 64) {
        int i = kept_idx[r];
        os[r] = tscore[b * NTOP + i];
        oc[r] = (float)tclass[b * NTOP + i];
        ob[r * 4 + 0] = tbox[(size_t)(b * NTOP + i) * 4 + 0];
        ob[r * 4 + 1] = tbox[(size_t)(b * NTOP + i) * 4 + 1];
        ob[r * 4 + 2] = tbox[(size_t)(b * NTOP + i) * 4 + 2];
        ob[r * 4 + 3] = tbox[(size_t)(b * NTOP + i) * 4 + 3];
    }
}

// ---------------------------------------------------------------- launch
extern "C" void kernel_launch(void* const* d_in, const int* in_sizes, int n_in,
                              void* d_out, int out_size, void* d_ws, size_t ws_size,
                              hipStream_t stream) {
    (void)in_sizes; (void)n_in; (void)out_size; (void)ws_size;
    // setup_inputs dict order is interleaved: cls0,reg0,cls1,reg1,...,cls4,reg4
    const float* cls[5];
    const float* reg[5];
    for (int i = 0; i < 5; ++i) {
        cls[i] = (const float*)d_in[2 * i];
        reg[i] = (const float*)d_in[2 * i + 1];
    }
    float* out = (float*)d_out;

    char* ws = (char*)d_ws;
    // ---- zero-init region (single memset) ----
    u32* ghist = (u32*)ws;           ws += (size_t)BB * NBIN * sizeof(u32);  // 512 KB
    u32* ccnt = (u32*)ws;            ws += 64;
    u32* maxcU = (u32*)ws;           ws += 64;
    size_t zbytes = (size_t)BB * NBIN * sizeof(u32) + 128;
    // ---- rest ----
    u32* Tbin = (u32*)ws;            ws += 64;
    u64* cand = (u64*)ws;            ws += (size_t)BB * NANCH * sizeof(u64);
    u64* sup = (u64*)ws;             ws += (size_t)BB * NTOP * NWORD * sizeof(u64);
    u32* akey = (u32*)ws;            ws += (size_t)BB * NANCH * sizeof(u32);
    float* ascore = (float*)ws;      ws += (size_t)BB * NANCH * sizeof(float);
    int* aclass = (int*)ws;          ws += (size_t)BB * NANCH * sizeof(int);
    float* abox = (float*)ws;        ws += (size_t)BB * NANCH * 4 * sizeof(float);
    float* tscore = (float*)ws;      ws += (size_t)BB * NTOP * sizeof(float);
    int* tclass = (int*)ws;          ws += (size_t)BB * NTOP * sizeof(int);
    float* tbox = (float*)ws;        ws += (size_t)BB * NTOP * 4 * sizeof(float);

    hipMemsetAsync(ghist, 0, zbytes, stream);

    dim3 gA((NANCH + 255) / 256, BB);
    k_anchor<<<gA, 256, 0, stream>>>(cls[0], cls[1], cls[2], cls[3], cls[4],
                                     reg[0], reg[1], reg[2], reg[3], reg[4],
                                     akey, ascore, aclass, abox, ghist);
    k_thresh<<<BB, 256, 0, stream>>>(ghist, Tbin);
    k_compact<<<gA, 256, 0, stream>>>(akey, Tbin, ccnt, cand);
    k_rank<<<dim3(32, BB), 256, 0, stream>>>(cand, ccnt, ascore, aclass, abox,
                                             tscore, tclass, tbox, maxcU);
    k_sup<<<dim3(16, 16, BB), 64, 0, stream>>>(tbox, tclass, maxcU, sup);
    k_scan<<<BB, 64, 0, stream>>>(sup, tscore, tclass, tbox, out);
}

// Round 3
// 394.211 us; speedup vs baseline: 1.2700x; 1.0542x over previous
//
#include <hip/hip_runtime.h>
#include <math.h>

typedef unsigned int u32;
typedef unsigned long long u64;

#define BB 16
#define NANCH 17064
#define NGRP 4266          // NANCH / 4
#define NTOP 1000
#define NWORD 16
#define NOUT 100
#define NBIN 8192

__device__ __forceinline__ u32 fmap(float v) {
    u32 u = __float_as_uint(v);
    return (u & 0x80000000u) ? ~u : (u | 0x80000000u);
}
__device__ __forceinline__ float funmap(u32 u) {
    u32 b = (u & 0x80000000u) ? (u & 0x7FFFFFFFu) : ~u;
    return __uint_as_float(b);
}

// ---------------------------------------------------------------- kernel A
// 2 threads per 4-anchor group (class halves 0-39 / 40-79), float4 loads
// over anchors, shfl_xor combine (half-0 wins ties == first-max argmax),
// per-block LDS histogram flushed once to global.
__global__ void __launch_bounds__(256) k_anchor(
        const float* __restrict__ c0, const float* __restrict__ c1,
        const float* __restrict__ c2, const float* __restrict__ c3,
        const float* __restrict__ c4,
        const float* __restrict__ r0, const float* __restrict__ r1,
        const float* __restrict__ r2, const float* __restrict__ r3,
        const float* __restrict__ r4,
        u32* __restrict__ akey, int* __restrict__ aclass,
        float* __restrict__ abox, u32* __restrict__ ghist) {
    __shared__ u32 lh[NBIN];                 // 32 KB
    int tid = threadIdx.x;
    int b = blockIdx.y;
    for (int i = tid; i < NBIN; i += 256) lh[i] = 0;
    __syncthreads();

    int gt = blockIdx.x * 256 + tid;         // 0 .. 8703 (2*NGRP = 8532 used)
    bool active = gt < 2 * NGRP;
    int p = gt >> 1, cs = gt & 1;            // group, class-half
    int a = p * 4;

    if (active) {
        const float *cp, *rp;
        int loc, wl, h, stride, half;
        if (a < 12800)      { loc = a;         wl = 7; h = 100; stride = 8;   half = 4;  cp = c0; rp = r0; }
        else if (a < 16000) { loc = a - 12800; wl = 6; h = 50;  stride = 16;  half = 8;  cp = c1; rp = r1; }
        else if (a < 16800) { loc = a - 16000; wl = 5; h = 25;  stride = 32;  half = 16; cp = c2; rp = r2; }
        else if (a < 17008) { loc = a - 16800; wl = 4; h = 13;  stride = 64;  half = 32; cp = c3; rp = r3; }
        else                { loc = a - 17008; wl = 3; h = 7;   stride = 128; half = 64; cp = c4; rp = r4; }
        int y = loc >> wl, x = loc & ((1 << wl) - 1);
        int hw = h << wl, hwq = hw >> 2;

        const float4* cb4 = (const float4*)(cp + (size_t)b * 80 * hw +
                                            (size_t)cs * 40 * hw + loc);
        int cbase = cs * 40;
        float4 v = cb4[0];
        float m0 = v.x, m1 = v.y, m2 = v.z, m3 = v.w;
        int a0 = cbase, a1 = cbase, a2 = cbase, a3 = cbase;
#pragma unroll 8
        for (int c = 1; c < 40; ++c) {
            float4 u = cb4[(size_t)c * hwq];
            int cc = cbase + c;
            if (u.x > m0) { m0 = u.x; a0 = cc; }
            if (u.y > m1) { m1 = u.y; a1 = cc; }
            if (u.z > m2) { m2 = u.z; a2 = cc; }
            if (u.w > m3) { m3 = u.w; a3 = cc; }
        }
        // combine halves: half-0 (A) wins ties -> first-max over 80 classes
        float pm0 = __shfl_xor(m0, 1), pm1 = __shfl_xor(m1, 1);
        float pm2 = __shfl_xor(m2, 1), pm3 = __shfl_xor(m3, 1);
        int pa0 = __shfl_xor(a0, 1), pa1 = __shfl_xor(a1, 1);
        int pa2 = __shfl_xor(a2, 1), pa3 = __shfl_xor(a3, 1);
        if (cs == 0) {
            float f0 = (m0 >= pm0) ? m0 : pm0;  int g0i = (m0 >= pm0) ? a0 : pa0;
            float f1 = (m1 >= pm1) ? m1 : pm1;  int g1i = (m1 >= pm1) ? a1 : pa1;
            float f2 = (m2 >= pm2) ? m2 : pm2;  int g2i = (m2 >= pm2) ? a2 : pa2;
            float f3 = (m3 >= pm3) ? m3 : pm3;  int g3i = (m3 >= pm3) ? a3 : pa3;

            const float4* rb4 = (const float4*)(rp + (size_t)b * 4 * hw + loc);
            float4 gl = rb4[0], gt_ = rb4[hwq], gr = rb4[2 * hwq], gb = rb4[3 * hwq];

            int idx = b * NANCH + a;
            u32 k0 = fmap(f0), k1 = fmap(f1), k2 = fmap(f2), k3 = fmap(f3);
            *(uint4*)(akey + idx) = make_uint4(k0, k1, k2, k3);
            *(int4*)(aclass + idx) = make_int4(g0i + 1, g1i + 1, g2i + 1, g3i + 1);
            float cy = (float)(y * stride + half);
            float cx0 = (float)(x * stride + half);
            float bx[4][4];
            float gls[4] = {gl.x, gl.y, gl.z, gl.w};
            float gts[4] = {gt_.x, gt_.y, gt_.z, gt_.w};
            float grs[4] = {gr.x, gr.y, gr.z, gr.w};
            float gbs[4] = {gb.x, gb.y, gb.z, gb.w};
#pragma unroll
            for (int k = 0; k < 4; ++k) {
                float cx = cx0 + (float)(k * stride);
                bx[k][0] = cx - gls[k];
                bx[k][1] = cy - gts[k];
                bx[k][2] = cx + grs[k];
                bx[k][3] = cy + gbs[k];
                *(float4*)(abox + (size_t)(idx + k) * 4) =
                    make_float4(bx[k][0], bx[k][1], bx[k][2], bx[k][3]);
            }
            atomicAdd(&lh[k0 >> 19], 1u);
            atomicAdd(&lh[k1 >> 19], 1u);
            atomicAdd(&lh[k2 >> 19], 1u);
            atomicAdd(&lh[k3 >> 19], 1u);
        }
    }
    __syncthreads();
    for (int i = tid; i < NBIN; i += 256) {
        u32 c = lh[i];
        if (c) atomicAdd(&ghist[b * NBIN + i], c);
    }
}

// ---------------------------------------------------------------- kernel B
__global__ void k_thresh(const u32* __restrict__ ghist, u32* __restrict__ Tbin) {
    __shared__ u32 seg[256];
    int b = blockIdx.x, t = threadIdx.x;
    const u32* h = ghist + b * NBIN;
    u32 s = 0;
    for (int i = 0; i < 32; ++i) s += h[t * 32 + i];
    seg[t] = s;
    __syncthreads();
    if (t == 0) {
        u32 acc = 0;
        int Tv = 0;
        for (int g = 255; g >= 0; --g) {
            if (acc + seg[g] >= NTOP) {
                for (int bin = g * 32 + 31; bin >= g * 32; --bin) {
                    acc += h[bin];
                    if (acc >= NTOP) { Tv = bin; break; }
                }
                break;
            }
            acc += seg[g];
        }
        Tbin[b] = (u32)Tv;
    }
}

// ---------------------------------------------------------------- kernel C
__global__ void k_compact(const u32* __restrict__ akey, const u32* __restrict__ Tbin,
                          u32* __restrict__ ccnt, u64* __restrict__ cand) {
    int a = blockIdx.x * blockDim.x + threadIdx.x;
    int b = blockIdx.y;
    if (a >= NANCH) return;
    u32 k = akey[b * NANCH + a];
    if ((k >> 19) >= Tbin[b]) {
        u32 p = atomicAdd(&ccnt[b], 1u);
        cand[b * NANCH + p] = ((u64)k << 32) | (u64)(0xFFFFFFFFu - (u32)a);
    }
}

// ---------------------------------------------------------------- kernel D
// exact rank -> scatter sorted top-1000; score recomputed from the invertible
// key (bitwise-identical to sigmoid of the original logit); fused max-coord.
__global__ void k_rank(const u64* __restrict__ cand, const u32* __restrict__ ccnt,
                       const int* __restrict__ aclass, const float* __restrict__ abox,
                       float* __restrict__ tscore, int* __restrict__ tclass,
                       float* __restrict__ tbox, u32* __restrict__ maxcU) {
    __shared__ u64 tile[1024];
    int b = blockIdx.y, tid = threadIdx.x;
    int C = (int)ccnt[b];
    const u64* ck = cand + b * NANCH;
    for (int base = blockIdx.x * 256; base < C; base += gridDim.x * 256) {
        int i = base + tid;
        bool have = i < C;
        u64 my = have ? ck[i] : 0ull;
        int rank = 0;
        for (int t0 = 0; t0 < C; t0 += 1024) {
            int nt = min(1024, C - t0);
            __syncthreads();
            for (int j = tid; j < nt; j += 256) tile[j] = ck[t0 + j];
            __syncthreads();
            if (have)
                for (int j = 0; j < nt; ++j) rank += (tile[j] > my) ? 1 : 0;
        }
        u32 mymax = 0;  // identity under monotone map
        if (have && rank < NTOP) {
            u32 a = 0xFFFFFFFFu - (u32)(my & 0xFFFFFFFFull);
            int src = b * NANCH + (int)a;
            int dst = b * NTOP + rank;
            float logit = funmap((u32)(my >> 32));
            float sc = 1.0f / (1.0f + expf(-logit));
            float b0 = abox[src * 4 + 0], b1 = abox[src * 4 + 1];
            float b2 = abox[src * 4 + 2], b3 = abox[src * 4 + 3];
            tscore[dst] = sc;
            tclass[dst] = aclass[src];
            tbox[dst * 4 + 0] = b0;
            tbox[dst * 4 + 1] = b1;
            tbox[dst * 4 + 2] = b2;
            tbox[dst * 4 + 3] = b3;
            if (sc >= 0.05f)
                mymax = fmap(fmaxf(fmaxf(b0, b1), fmaxf(b2, b3)));
        }
        for (int off = 32; off > 0; off >>= 1) {
            u32 o = (u32)__shfl_down((int)mymax, off);
            mymax = mymax > o ? mymax : o;
        }
        if ((tid & 63) == 0) atomicMax(&maxcU[b], mymax);
    }
}

// ---------------------------------------------------------------- kernel F
// upper-triangle tiles only (136 of 256); lower-tile words never read by scan
__global__ void k_sup(const float* __restrict__ tbox, const int* __restrict__ tclass,
                      const u32* __restrict__ maxcU, u64* __restrict__ sup) {
    int u = blockIdx.x, b = blockIdx.y;
    int ti = 0, rem = u;
    while (rem >= NWORD - ti) { rem -= NWORD - ti; ++ti; }
    int tj = ti + rem;
    int t = threadIdx.x;
    __shared__ double jx1[64], jy1[64], jx2[64], jy2[64], jcx[64], jcy[64], jar[64];
    double mc1 = (double)funmap(maxcU[b]) + 1.0;
    int j = tj * 64 + t;
    if (j < NTOP) {
        const float* bx = tbox + (size_t)(b * NTOP + j) * 4;
        double o = (double)tclass[b * NTOP + j] * mc1;
        double x1 = (double)bx[0] + o, y1 = (double)bx[1] + o;
        double x2 = (double)bx[2] + o, y2 = (double)bx[3] + o;
        jx1[t] = x1; jy1[t] = y1; jx2[t] = x2; jy2[t] = y2;
        jcx[t] = (x1 + x2) * 0.5; jcy[t] = (y1 + y2) * 0.5;
        jar[t] = (x2 - x1 + 1.0) * (y2 - y1 + 1.0);
    }
    __syncthreads();
    int i = ti * 64 + t;
    if (i >= NTOP) return;
    const float* bx = tbox + (size_t)(b * NTOP + i) * 4;
    double o = (double)tclass[b * NTOP + i] * mc1;
    double ix1 = (double)bx[0] + o, iy1 = (double)bx[1] + o;
    double ix2 = (double)bx[2] + o, iy2 = (double)bx[3] + o;
    double icx = (ix1 + ix2) * 0.5, icy = (iy1 + iy2) * 0.5;
    double iar = (ix2 - ix1 + 1.0) * (iy2 - iy1 + 1.0);
    u64 bits = 0;
    int jbase = tj * 64;
    for (int jj = 0; jj < 64; ++jj) {
        int jg = jbase + jj;
        if (jg >= NTOP) break;
        if (jg <= i) continue;
        double xm = fmax(ix1, jx1[jj]), ym = fmax(iy1, jy1[jj]);
        double xM = fmin(ix2, jx2[jj]), yM = fmin(iy2, jy2[jj]);
        double inter = fmax(xM - xm, 0.0) * fmax(yM - ym, 0.0);
        double iou = inter / (iar + jar[jj] - inter);
        double dx = icx - jcx[jj], dy = icy - jcy[jj];
        double idg = dx * dx + dy * dy;
        double ox = fmax(ix2, jx2[jj]) - fmin(ix1, jx1[jj]);
        double oy = fmax(iy2, jy2[jj]) - fmin(iy1, jy1[jj]);
        double odg = ox * ox + oy * oy;
        double diou = iou - idg / fmax(odg, 1e-12);
        if (diou > 0.6) bits |= (1ull << jj);
    }
    sup[(size_t)(b * NTOP + i) * NWORD + tj] = bits;
}

// ---------------------------------------------------------------- kernel G
__global__ void k_scan(const u64* __restrict__ sup, const float* __restrict__ tscore,
                       const int* __restrict__ tclass, const float* __restrict__ tbox,
                       float* __restrict__ out) {
    int b = blockIdx.x, lane = threadIdx.x;  // 64 threads
    __shared__ u64 rows[64 * NWORD];
    __shared__ int kept_idx[NOUT];
    u64 remv[NWORD], valid[NWORD];
#pragma unroll
    for (int w = 0; w < NWORD; ++w) remv[w] = 0;
#pragma unroll
    for (int t = 0; t < NWORD; ++t) {
        int i = t * 64 + lane;
        float s = (i < NTOP) ? tscore[b * NTOP + i] : -1.0f;
        valid[t] = __ballot(s >= 0.05f);
    }
    const u64* supb = sup + (size_t)b * NTOP * NWORD;
    int kept = 0;
    for (int t = 0; t < NWORD && kept < NOUT; ++t) {
        __syncthreads();
        for (int q = 0; q < NWORD; ++q) {
            int idx = q * 64 + lane;
            int r = t * 64 + (idx >> 4);
            rows[idx] = (r < NTOP) ? supb[(size_t)t * 1024 + idx] : 0ull;
        }
        __syncthreads();
        int nr = min(64, NTOP - t * 64);
        for (int k = 0; k < nr; ++k) {
            bool keep = (((valid[t] >> k) & 1ull) != 0ull) &&
                        (((remv[t] >> k) & 1ull) == 0ull);
            if (keep) {
                for (int w = t; w < NWORD; ++w) remv[w] |= rows[k * NWORD + w];
                if (lane == 0) kept_idx[kept] = t * 64 + k;
                ++kept;
                if (kept >= NOUT) break;
            }
        }
    }
    __syncthreads();
    float* os = out + b * NOUT;
    float* oc = out + BB * NOUT + b * NOUT;
    float* ob = out + 2 * BB * NOUT + (size_t)b * NOUT * 4;
    for (int i = lane; i < NOUT; i += 64) { os[i] = -2.0f; oc[i] = -2.0f; }
    for (int i = lane; i < NOUT * 4; i += 64) ob[i] = -2.0f;
    __syncthreads();
    int ncopy = kept < NOUT ? kept : NOUT;
    for (int r = lane; r < ncopy; r += 64) {
        int i = kept_idx[r];
        os[r] = tscore[b * NTOP + i];
        oc[r] = (float)tclass[b * NTOP + i];
        ob[r * 4 + 0] = tbox[(size_t)(b * NTOP + i) * 4 + 0];
        ob[r * 4 + 1] = tbox[(size_t)(b * NTOP + i) * 4 + 1];
        ob[r * 4 + 2] = tbox[(size_t)(b * NTOP + i) * 4 + 2];
        ob[r * 4 + 3] = tbox[(size_t)(b * NTOP + i) * 4 + 3];
    }
}

// ---------------------------------------------------------------- launch
extern "C" void kernel_launch(void* const* d_in, const int* in_sizes, int n_in,
                              void* d_out, int out_size, void* d_ws, size_t ws_size,
                              hipStream_t stream) {
    (void)in_sizes; (void)n_in; (void)out_size; (void)ws_size;
    const float* cls[5];
    const float* reg[5];
    for (int i = 0; i < 5; ++i) {
        cls[i] = (const float*)d_in[2 * i];
        reg[i] = (const float*)d_in[2 * i + 1];
    }
    float* out = (float*)d_out;

    char* ws = (char*)d_ws;
    // ---- zero-init region (single memset) ----
    u32* ghist = (u32*)ws;           ws += (size_t)BB * NBIN * sizeof(u32);  // 512 KB
    u32* ccnt = (u32*)ws;            ws += 64;
    u32* maxcU = (u32*)ws;           ws += 64;
    size_t zbytes = (size_t)BB * NBIN * sizeof(u32) + 128;
    // ---- rest ----
    u32* Tbin = (u32*)ws;            ws += 64;
    u64* cand = (u64*)ws;            ws += (size_t)BB * NANCH * sizeof(u64);
    u64* sup = (u64*)ws;             ws += (size_t)BB * NTOP * NWORD * sizeof(u64);
    u32* akey = (u32*)ws;            ws += (size_t)BB * NANCH * sizeof(u32);
    int* aclass = (int*)ws;          ws += (size_t)BB * NANCH * sizeof(int);
    float* abox = (float*)ws;        ws += (size_t)BB * NANCH * 4 * sizeof(float);
    float* tscore = (float*)ws;      ws += (size_t)BB * NTOP * sizeof(float);
    int* tclass = (int*)ws;          ws += (size_t)BB * NTOP * sizeof(int);
    float* tbox = (float*)ws;        ws += (size_t)BB * NTOP * 4 * sizeof(float);

    hipMemsetAsync(ghist, 0, zbytes, stream);

    k_anchor<<<dim3((2 * NGRP + 255) / 256, BB), 256, 0, stream>>>(
        cls[0], cls[1], cls[2], cls[3], cls[4],
        reg[0], reg[1], reg[2], reg[3], reg[4],
        akey, aclass, abox, ghist);
    k_thresh<<<BB, 256, 0, stream>>>(ghist, Tbin);
    k_compact<<<dim3((NANCH + 255) / 256, BB), 256, 0, stream>>>(akey, Tbin, ccnt, cand);
    k_rank<<<dim3(32, BB), 256, 0, stream>>>(cand, ccnt, aclass, abox,
                                             tscore, tclass, tbox, maxcU);
    k_sup<<<dim3(136, BB), 64, 0, stream>>>(tbox, tclass, maxcU, sup);
    k_scan<<<BB, 64, 0, stream>>>(sup, tscore, tclass, tbox, out);
}

// Round 4
// 381.024 us; speedup vs baseline: 1.3140x; 1.0346x over previous
//
#include <hip/hip_runtime.h>
#include <math.h>

typedef unsigned int u32;
typedef unsigned long long u64;

#define BB 16
#define NANCH 17064
#define NGRP 4266          // NANCH / 4
#define NTOP 1000
#define NWORD 16
#define NOUT 100
#define NBIN 8192

__device__ __forceinline__ u32 fmap(float v) {
    u32 u = __float_as_uint(v);
    return (u & 0x80000000u) ? ~u : (u | 0x80000000u);
}
__device__ __forceinline__ float funmap(u32 u) {
    u32 b = (u & 0x80000000u) ? (u & 0x7FFFFFFFu) : ~u;
    return __uint_as_float(b);
}

// ---------------------------------------------------------------- kernel A
// 4 threads per 4-anchor group (20 classes each), float4 loads over anchors,
// two-stage shfl_xor combine (lower class-half wins ties == first-max argmax),
// per-block LDS histogram flushed once to global.
__global__ void __launch_bounds__(256) k_anchor(
        const float* __restrict__ c0, const float* __restrict__ c1,
        const float* __restrict__ c2, const float* __restrict__ c3,
        const float* __restrict__ c4,
        const float* __restrict__ r0, const float* __restrict__ r1,
        const float* __restrict__ r2, const float* __restrict__ r3,
        const float* __restrict__ r4,
        u32* __restrict__ akey, int* __restrict__ aclass,
        float* __restrict__ abox, u32* __restrict__ ghist) {
    __shared__ u32 lh[NBIN];                 // 32 KB
    int tid = threadIdx.x;
    int b = blockIdx.y;
    for (int i = tid; i < NBIN; i += 256) lh[i] = 0;
    __syncthreads();

    int gt = blockIdx.x * 256 + tid;         // 4 * NGRP = 17064 used
    bool active = gt < 4 * NGRP;
    int p = gt >> 2, cs = gt & 3;            // group, class-quarter
    int a = p * 4;

    if (active) {
        const float *cp, *rp;
        int loc, wl, h, stride, half;
        if (a < 12800)      { loc = a;         wl = 7; h = 100; stride = 8;   half = 4;  cp = c0; rp = r0; }
        else if (a < 16000) { loc = a - 12800; wl = 6; h = 50;  stride = 16;  half = 8;  cp = c1; rp = r1; }
        else if (a < 16800) { loc = a - 16000; wl = 5; h = 25;  stride = 32;  half = 16; cp = c2; rp = r2; }
        else if (a < 17008) { loc = a - 16800; wl = 4; h = 13;  stride = 64;  half = 32; cp = c3; rp = r3; }
        else                { loc = a - 17008; wl = 3; h = 7;   stride = 128; half = 64; cp = c4; rp = r4; }
        int y = loc >> wl, x = loc & ((1 << wl) - 1);
        int hw = h << wl, hwq = hw >> 2;

        const float4* cb4 = (const float4*)(cp + (size_t)b * 80 * hw +
                                            (size_t)cs * 20 * hw + loc);
        int cbase = cs * 20;
        float4 v = cb4[0];
        float m0 = v.x, m1 = v.y, m2 = v.z, m3 = v.w;
        int a0 = cbase, a1 = cbase, a2 = cbase, a3 = cbase;
#pragma unroll 10
        for (int c = 1; c < 20; ++c) {
            float4 u = cb4[(size_t)c * hwq];
            int cc = cbase + c;
            if (u.x > m0) { m0 = u.x; a0 = cc; }
            if (u.y > m1) { m1 = u.y; a1 = cc; }
            if (u.z > m2) { m2 = u.z; a2 = cc; }
            if (u.w > m3) { m3 = u.w; a3 = cc; }
        }
        // stage 1: combine with xor-1 partner; lower class-quarter wins ties
        {
            bool low = (cs & 1) == 0;
            float pm; int pa; bool tk;
            pm = __shfl_xor(m0, 1); pa = __shfl_xor(a0, 1);
            tk = low ? (m0 >= pm) : (m0 > pm); m0 = tk ? m0 : pm; a0 = tk ? a0 : pa;
            pm = __shfl_xor(m1, 1); pa = __shfl_xor(a1, 1);
            tk = low ? (m1 >= pm) : (m1 > pm); m1 = tk ? m1 : pm; a1 = tk ? a1 : pa;
            pm = __shfl_xor(m2, 1); pa = __shfl_xor(a2, 1);
            tk = low ? (m2 >= pm) : (m2 > pm); m2 = tk ? m2 : pm; a2 = tk ? a2 : pa;
            pm = __shfl_xor(m3, 1); pa = __shfl_xor(a3, 1);
            tk = low ? (m3 >= pm) : (m3 > pm); m3 = tk ? m3 : pm; a3 = tk ? a3 : pa;
        }
        // stage 2: combine with xor-2 partner; lower half wins ties
        {
            bool low = (cs & 2) == 0;
            float pm; int pa; bool tk;
            pm = __shfl_xor(m0, 2); pa = __shfl_xor(a0, 2);
            tk = low ? (m0 >= pm) : (m0 > pm); m0 = tk ? m0 : pm; a0 = tk ? a0 : pa;
            pm = __shfl_xor(m1, 2); pa = __shfl_xor(a1, 2);
            tk = low ? (m1 >= pm) : (m1 > pm); m1 = tk ? m1 : pm; a1 = tk ? a1 : pa;
            pm = __shfl_xor(m2, 2); pa = __shfl_xor(a2, 2);
            tk = low ? (m2 >= pm) : (m2 > pm); m2 = tk ? m2 : pm; a2 = tk ? a2 : pa;
            pm = __shfl_xor(m3, 2); pa = __shfl_xor(a3, 2);
            tk = low ? (m3 >= pm) : (m3 > pm); m3 = tk ? m3 : pm; a3 = tk ? a3 : pa;
        }
        if (cs == 0) {
            const float4* rb4 = (const float4*)(rp + (size_t)b * 4 * hw + loc);
            float4 gl = rb4[0], gt_ = rb4[hwq], gr = rb4[2 * hwq], gb = rb4[3 * hwq];

            int idx = b * NANCH + a;
            u32 k0 = fmap(m0), k1 = fmap(m1), k2 = fmap(m2), k3 = fmap(m3);
            *(uint4*)(akey + idx) = make_uint4(k0, k1, k2, k3);
            *(int4*)(aclass + idx) = make_int4(a0 + 1, a1 + 1, a2 + 1, a3 + 1);
            float cy = (float)(y * stride + half);
            float cx0 = (float)(x * stride + half);
            float gls[4] = {gl.x, gl.y, gl.z, gl.w};
            float gts[4] = {gt_.x, gt_.y, gt_.z, gt_.w};
            float grs[4] = {gr.x, gr.y, gr.z, gr.w};
            float gbs[4] = {gb.x, gb.y, gb.z, gb.w};
#pragma unroll
            for (int k = 0; k < 4; ++k) {
                float cx = cx0 + (float)(k * stride);
                *(float4*)(abox + (size_t)(idx + k) * 4) =
                    make_float4(cx - gls[k], cy - gts[k], cx + grs[k], cy + gbs[k]);
            }
            atomicAdd(&lh[k0 >> 19], 1u);
            atomicAdd(&lh[k1 >> 19], 1u);
            atomicAdd(&lh[k2 >> 19], 1u);
            atomicAdd(&lh[k3 >> 19], 1u);
        }
    }
    __syncthreads();
    for (int i = tid; i < NBIN; i += 256) {
        u32 c = lh[i];
        if (c) atomicAdd(&ghist[b * NBIN + i], c);
    }
}

// ---------------------------------------------------------------- kernel B
__global__ void k_thresh(const u32* __restrict__ ghist, u32* __restrict__ Tbin) {
    __shared__ u32 seg[256];
    int b = blockIdx.x, t = threadIdx.x;
    const u32* h = ghist + b * NBIN;
    u32 s = 0;
    for (int i = 0; i < 32; ++i) s += h[t * 32 + i];
    seg[t] = s;
    __syncthreads();
    if (t == 0) {
        u32 acc = 0;
        int Tv = 0;
        for (int g = 255; g >= 0; --g) {
            if (acc + seg[g] >= NTOP) {
                for (int bin = g * 32 + 31; bin >= g * 32; --bin) {
                    acc += h[bin];
                    if (acc >= NTOP) { Tv = bin; break; }
                }
                break;
            }
            acc += seg[g];
        }
        Tbin[b] = (u32)Tv;
    }
}

// ---------------------------------------------------------------- kernel C
__global__ void k_compact(const u32* __restrict__ akey, const u32* __restrict__ Tbin,
                          u32* __restrict__ ccnt, u64* __restrict__ cand) {
    int a = blockIdx.x * blockDim.x + threadIdx.x;
    int b = blockIdx.y;
    if (a >= NANCH) return;
    u32 k = akey[b * NANCH + a];
    if ((k >> 19) >= Tbin[b]) {
        u32 p = atomicAdd(&ccnt[b], 1u);
        cand[b * NANCH + p] = ((u64)k << 32) | (u64)(0xFFFFFFFFu - (u32)a);
    }
}

// ---------------------------------------------------------------- kernel D
__global__ void k_rank(const u64* __restrict__ cand, const u32* __restrict__ ccnt,
                       const int* __restrict__ aclass, const float* __restrict__ abox,
                       float* __restrict__ tscore, int* __restrict__ tclass,
                       float* __restrict__ tbox, u32* __restrict__ maxcU) {
    __shared__ u64 tile[1024];
    int b = blockIdx.y, tid = threadIdx.x;
    int C = (int)ccnt[b];
    const u64* ck = cand + b * NANCH;
    for (int base = blockIdx.x * 256; base < C; base += gridDim.x * 256) {
        int i = base + tid;
        bool have = i < C;
        u64 my = have ? ck[i] : 0ull;
        int rank = 0;
        for (int t0 = 0; t0 < C; t0 += 1024) {
            int nt = min(1024, C - t0);
            __syncthreads();
            for (int j = tid; j < nt; j += 256) tile[j] = ck[t0 + j];
            __syncthreads();
            if (have)
                for (int j = 0; j < nt; ++j) rank += (tile[j] > my) ? 1 : 0;
        }
        u32 mymax = 0;  // identity under monotone map
        if (have && rank < NTOP) {
            u32 a = 0xFFFFFFFFu - (u32)(my & 0xFFFFFFFFull);
            int src = b * NANCH + (int)a;
            int dst = b * NTOP + rank;
            float logit = funmap((u32)(my >> 32));
            float sc = 1.0f / (1.0f + expf(-logit));
            float b0 = abox[src * 4 + 0], b1 = abox[src * 4 + 1];
            float b2 = abox[src * 4 + 2], b3 = abox[src * 4 + 3];
            tscore[dst] = sc;
            tclass[dst] = aclass[src];
            tbox[dst * 4 + 0] = b0;
            tbox[dst * 4 + 1] = b1;
            tbox[dst * 4 + 2] = b2;
            tbox[dst * 4 + 3] = b3;
            if (sc >= 0.05f)
                mymax = fmap(fmaxf(fmaxf(b0, b1), fmaxf(b2, b3)));
        }
        for (int off = 32; off > 0; off >>= 1) {
            u32 o = (u32)__shfl_down((int)mymax, off);
            mymax = mymax > o ? mymax : o;
        }
        if ((tid & 63) == 0) atomicMax(&maxcU[b], mymax);
    }
}

// ---------------------------------------------------------------- kernel F
// upper-triangle tiles only (136 of 256)
__global__ void k_sup(const float* __restrict__ tbox, const int* __restrict__ tclass,
                      const u32* __restrict__ maxcU, u64* __restrict__ sup) {
    int u = blockIdx.x, b = blockIdx.y;
    int ti = 0, rem = u;
    while (rem >= NWORD - ti) { rem -= NWORD - ti; ++ti; }
    int tj = ti + rem;
    int t = threadIdx.x;
    __shared__ double jx1[64], jy1[64], jx2[64], jy2[64], jcx[64], jcy[64], jar[64];
    double mc1 = (double)funmap(maxcU[b]) + 1.0;
    int j = tj * 64 + t;
    if (j < NTOP) {
        const float* bx = tbox + (size_t)(b * NTOP + j) * 4;
        double o = (double)tclass[b * NTOP + j] * mc1;
        double x1 = (double)bx[0] + o, y1 = (double)bx[1] + o;
        double x2 = (double)bx[2] + o, y2 = (double)bx[3] + o;
        jx1[t] = x1; jy1[t] = y1; jx2[t] = x2; jy2[t] = y2;
        jcx[t] = (x1 + x2) * 0.5; jcy[t] = (y1 + y2) * 0.5;
        jar[t] = (x2 - x1 + 1.0) * (y2 - y1 + 1.0);
    }
    __syncthreads();
    int i = ti * 64 + t;
    if (i >= NTOP) return;
    const float* bx = tbox + (size_t)(b * NTOP + i) * 4;
    double o = (double)tclass[b * NTOP + i] * mc1;
    double ix1 = (double)bx[0] + o, iy1 = (double)bx[1] + o;
    double ix2 = (double)bx[2] + o, iy2 = (double)bx[3] + o;
    double icx = (ix1 + ix2) * 0.5, icy = (iy1 + iy2) * 0.5;
    double iar = (ix2 - ix1 + 1.0) * (iy2 - iy1 + 1.0);
    u64 bits = 0;
    int jbase = tj * 64;
    for (int jj = 0; jj < 64; ++jj) {
        int jg = jbase + jj;
        if (jg >= NTOP) break;
        if (jg <= i) continue;
        double xm = fmax(ix1, jx1[jj]), ym = fmax(iy1, jy1[jj]);
        double xM = fmin(ix2, jx2[jj]), yM = fmin(iy2, jy2[jj]);
        double inter = fmax(xM - xm, 0.0) * fmax(yM - ym, 0.0);
        double iou = inter / (iar + jar[jj] - inter);
        double dx = icx - jcx[jj], dy = icy - jcy[jj];
        double idg = dx * dx + dy * dy;
        double ox = fmax(ix2, jx2[jj]) - fmin(ix1, jx1[jj]);
        double oy = fmax(iy2, jy2[jj]) - fmin(iy1, jy1[jj]);
        double odg = ox * ox + oy * oy;
        double diou = iou - idg / fmax(odg, 1e-12);
        if (diou > 0.6) bits |= (1ull << jj);
    }
    sup[(size_t)(b * NTOP + i) * NWORD + tj] = bits;
}

// ---------------------------------------------------------------- kernel G
// fully-unrolled tile loop: remv[]/valid[] have static indices everywhere ->
// promoted to registers (no scratch). Early-exit at 100 kept.
__global__ void k_scan(const u64* __restrict__ sup, const float* __restrict__ tscore,
                       const int* __restrict__ tclass, const float* __restrict__ tbox,
                       float* __restrict__ out) {
    int b = blockIdx.x, lane = threadIdx.x;  // 64 threads
    __shared__ u64 rows[64 * NWORD];
    __shared__ int kept_idx[NOUT];
    u64 remv[NWORD], valid[NWORD];
#pragma unroll
    for (int w = 0; w < NWORD; ++w) remv[w] = 0;
#pragma unroll
    for (int w = 0; w < NWORD; ++w) {
        int i = w * 64 + lane;
        float s = (i < NTOP) ? tscore[b * NTOP + i] : -1.0f;
        valid[w] = __ballot(s >= 0.05f);
    }
    const u64* supb = sup + (size_t)b * NTOP * NWORD;
    int kept = 0;
#pragma unroll
    for (int t = 0; t < NWORD; ++t) {      // unrolled: t is compile-time const
        if (kept >= NOUT) break;
        __syncthreads();
        for (int q = 0; q < NWORD; ++q) {
            int idx = q * 64 + lane;
            int r = t * 64 + (idx >> 4);
            rows[idx] = (r < NTOP) ? supb[(size_t)t * 1024 + idx] : 0ull;
        }
        __syncthreads();
        int nr = min(64, NTOP - t * 64);
        for (int k = 0; k < nr; ++k) {
            bool keep = (((valid[t] >> k) & 1ull) != 0ull) &&
                        (((remv[t] >> k) & 1ull) == 0ull);
            if (keep) {                     // wave-uniform
#pragma unroll
                for (int w = t; w < NWORD; ++w) remv[w] |= rows[k * NWORD + w];
                if (lane == 0) kept_idx[kept] = t * 64 + k;
                ++kept;
                if (kept >= NOUT) break;
            }
        }
    }
    __syncthreads();
    float* os = out + b * NOUT;
    float* oc = out + BB * NOUT + b * NOUT;
    float* ob = out + 2 * BB * NOUT + (size_t)b * NOUT * 4;
    for (int i = lane; i < NOUT; i += 64) { os[i] = -2.0f; oc[i] = -2.0f; }
    for (int i = lane; i < NOUT * 4; i += 64) ob[i] = -2.0f;
    __syncthreads();
    int ncopy = kept < NOUT ? kept : NOUT;
    for (int r = lane; r < ncopy; r += 64) {
        int i = kept_idx[r];
        os[r] = tscore[b * NTOP + i];
        oc[r] = (float)tclass[b * NTOP + i];
        ob[r * 4 + 0] = tbox[(size_t)(b * NTOP + i) * 4 + 0];
        ob[r * 4 + 1] = tbox[(size_t)(b * NTOP + i) * 4 + 1];
        ob[r * 4 + 2] = tbox[(size_t)(b * NTOP + i) * 4 + 2];
        ob[r * 4 + 3] = tbox[(size_t)(b * NTOP + i) * 4 + 3];
    }
}

// ---------------------------------------------------------------- launch
extern "C" void kernel_launch(void* const* d_in, const int* in_sizes, int n_in,
                              void* d_out, int out_size, void* d_ws, size_t ws_size,
                              hipStream_t stream) {
    (void)in_sizes; (void)n_in; (void)out_size; (void)ws_size;
    const float* cls[5];
    const float* reg[5];
    for (int i = 0; i < 5; ++i) {
        cls[i] = (const float*)d_in[2 * i];
        reg[i] = (const float*)d_in[2 * i + 1];
    }
    float* out = (float*)d_out;

    char* ws = (char*)d_ws;
    // ---- zero-init region (single memset) ----
    u32* ghist = (u32*)ws;           ws += (size_t)BB * NBIN * sizeof(u32);  // 512 KB
    u32* ccnt = (u32*)ws;            ws += 64;
    u32* maxcU = (u32*)ws;           ws += 64;
    size_t zbytes = (size_t)BB * NBIN * sizeof(u32) + 128;
    // ---- rest ----
    u32* Tbin = (u32*)ws;            ws += 64;
    u64* cand = (u64*)ws;            ws += (size_t)BB * NANCH * sizeof(u64);
    u64* sup = (u64*)ws;             ws += (size_t)BB * NTOP * NWORD * sizeof(u64);
    u32* akey = (u32*)ws;            ws += (size_t)BB * NANCH * sizeof(u32);
    int* aclass = (int*)ws;          ws += (size_t)BB * NANCH * sizeof(int);
    float* abox = (float*)ws;        ws += (size_t)BB * NANCH * 4 * sizeof(float);
    float* tscore = (float*)ws;      ws += (size_t)BB * NTOP * sizeof(float);
    int* tclass = (int*)ws;          ws += (size_t)BB * NTOP * sizeof(int);
    float* tbox = (float*)ws;        ws += (size_t)BB * NTOP * 4 * sizeof(float);

    hipMemsetAsync(ghist, 0, zbytes, stream);

    k_anchor<<<dim3((4 * NGRP + 255) / 256, BB), 256, 0, stream>>>(
        cls[0], cls[1], cls[2], cls[3], cls[4],
        reg[0], reg[1], reg[2], reg[3], reg[4],
        akey, aclass, abox, ghist);
    k_thresh<<<BB, 256, 0, stream>>>(ghist, Tbin);
    k_compact<<<dim3((NANCH + 255) / 256, BB), 256, 0, stream>>>(akey, Tbin, ccnt, cand);
    k_rank<<<dim3(32, BB), 256, 0, stream>>>(cand, ccnt, aclass, abox,
                                             tscore, tclass, tbox, maxcU);
    k_sup<<<dim3(136, BB), 64, 0, stream>>>(tbox, tclass, maxcU, sup);
    k_scan<<<BB, 64, 0, stream>>>(sup, tscore, tclass, tbox, out);
}

// Round 5
// 298.376 us; speedup vs baseline: 1.6779x; 1.2770x over previous
//
#include <hip/hip_runtime.h>
#include <math.h>

typedef unsigned int u32;
typedef unsigned long long u64;

#define BB 16
#define NANCH 17064
#define NGRP 4266          // NANCH / 4
#define NTOP 1000
#define NWORD 16
#define NOUT 100
#define NBIN 8192

__device__ __forceinline__ u32 fmap(float v) {
    u32 u = __float_as_uint(v);
    return (u & 0x80000000u) ? ~u : (u | 0x80000000u);
}
__device__ __forceinline__ float funmap(u32 u) {
    u32 b = (u & 0x80000000u) ? (u & 0x7FFFFFFFu) : ~u;
    return __uint_as_float(b);
}

// ---------------------------------------------------------------- kernel A
// Pure streaming: 4 threads per 4-anchor group (20 classes each), float4
// loads, two-stage shfl_xor combine (lower class-quarter wins ties ==
// first-max argmax). No LDS, no atomics.
__global__ void __launch_bounds__(256) k_anchor(
        const float* __restrict__ c0, const float* __restrict__ c1,
        const float* __restrict__ c2, const float* __restrict__ c3,
        const float* __restrict__ c4,
        const float* __restrict__ r0, const float* __restrict__ r1,
        const float* __restrict__ r2, const float* __restrict__ r3,
        const float* __restrict__ r4,
        u32* __restrict__ akey, int* __restrict__ aclass,
        float* __restrict__ abox) {
    int tid = threadIdx.x;
    int b = blockIdx.y;
    int gt = blockIdx.x * 256 + tid;         // 4 * NGRP = 17064 used
    if (gt >= 4 * NGRP) return;
    int p = gt >> 2, cs = gt & 3;            // group, class-quarter
    int a = p * 4;

    const float *cp, *rp;
    int loc, wl, h, stride, half;
    if (a < 12800)      { loc = a;         wl = 7; h = 100; stride = 8;   half = 4;  cp = c0; rp = r0; }
    else if (a < 16000) { loc = a - 12800; wl = 6; h = 50;  stride = 16;  half = 8;  cp = c1; rp = r1; }
    else if (a < 16800) { loc = a - 16000; wl = 5; h = 25;  stride = 32;  half = 16; cp = c2; rp = r2; }
    else if (a < 17008) { loc = a - 16800; wl = 4; h = 13;  stride = 64;  half = 32; cp = c3; rp = r3; }
    else                { loc = a - 17008; wl = 3; h = 7;   stride = 128; half = 64; cp = c4; rp = r4; }
    int y = loc >> wl, x = loc & ((1 << wl) - 1);
    int hw = h << wl, hwq = hw >> 2;

    const float4* cb4 = (const float4*)(cp + (size_t)b * 80 * hw +
                                        (size_t)cs * 20 * hw + loc);
    int cbase = cs * 20;
    float4 v = cb4[0];
    float m0 = v.x, m1 = v.y, m2 = v.z, m3 = v.w;
    int a0 = cbase, a1 = cbase, a2 = cbase, a3 = cbase;
#pragma unroll
    for (int c = 1; c < 20; ++c) {
        float4 u = cb4[(size_t)c * hwq];
        int cc = cbase + c;
        if (u.x > m0) { m0 = u.x; a0 = cc; }
        if (u.y > m1) { m1 = u.y; a1 = cc; }
        if (u.z > m2) { m2 = u.z; a2 = cc; }
        if (u.w > m3) { m3 = u.w; a3 = cc; }
    }
    // stage 1: xor-1 partner; lower class-quarter wins ties
    {
        bool low = (cs & 1) == 0;
        float pm; int pa; bool tk;
        pm = __shfl_xor(m0, 1); pa = __shfl_xor(a0, 1);
        tk = low ? (m0 >= pm) : (m0 > pm); m0 = tk ? m0 : pm; a0 = tk ? a0 : pa;
        pm = __shfl_xor(m1, 1); pa = __shfl_xor(a1, 1);
        tk = low ? (m1 >= pm) : (m1 > pm); m1 = tk ? m1 : pm; a1 = tk ? a1 : pa;
        pm = __shfl_xor(m2, 1); pa = __shfl_xor(a2, 1);
        tk = low ? (m2 >= pm) : (m2 > pm); m2 = tk ? m2 : pm; a2 = tk ? a2 : pa;
        pm = __shfl_xor(m3, 1); pa = __shfl_xor(a3, 1);
        tk = low ? (m3 >= pm) : (m3 > pm); m3 = tk ? m3 : pm; a3 = tk ? a3 : pa;
    }
    // stage 2: xor-2 partner; lower half wins ties
    {
        bool low = (cs & 2) == 0;
        float pm; int pa; bool tk;
        pm = __shfl_xor(m0, 2); pa = __shfl_xor(a0, 2);
        tk = low ? (m0 >= pm) : (m0 > pm); m0 = tk ? m0 : pm; a0 = tk ? a0 : pa;
        pm = __shfl_xor(m1, 2); pa = __shfl_xor(a1, 2);
        tk = low ? (m1 >= pm) : (m1 > pm); m1 = tk ? m1 : pm; a1 = tk ? a1 : pa;
        pm = __shfl_xor(m2, 2); pa = __shfl_xor(a2, 2);
        tk = low ? (m2 >= pm) : (m2 > pm); m2 = tk ? m2 : pm; a2 = tk ? a2 : pa;
        pm = __shfl_xor(m3, 2); pa = __shfl_xor(a3, 2);
        tk = low ? (m3 >= pm) : (m3 > pm); m3 = tk ? m3 : pm; a3 = tk ? a3 : pa;
    }
    if (cs == 0) {
        const float4* rb4 = (const float4*)(rp + (size_t)b * 4 * hw + loc);
        float4 gl = rb4[0], gt_ = rb4[hwq], gr = rb4[2 * hwq], gb = rb4[3 * hwq];

        int idx = b * NANCH + a;
        *(uint4*)(akey + idx) = make_uint4(fmap(m0), fmap(m1), fmap(m2), fmap(m3));
        *(int4*)(aclass + idx) = make_int4(a0 + 1, a1 + 1, a2 + 1, a3 + 1);
        float cy = (float)(y * stride + half);
        float cx0 = (float)(x * stride + half);
        float gls[4] = {gl.x, gl.y, gl.z, gl.w};
        float gts[4] = {gt_.x, gt_.y, gt_.z, gt_.w};
        float grs[4] = {gr.x, gr.y, gr.z, gr.w};
        float gbs[4] = {gb.x, gb.y, gb.z, gb.w};
#pragma unroll
        for (int k = 0; k < 4; ++k) {
            float cx = cx0 + (float)(k * stride);
            *(float4*)(abox + (size_t)(idx + k) * 4) =
                make_float4(cx - gls[k], cy - gts[k], cx + grs[k], cy + gbs[k]);
        }
    }
}

// ---------------------------------------------------------------- kernel B
// fused per-batch: LDS histogram -> threshold bin -> compact candidates.
// Also zero-inits maxcU and writes ccnt (no global memset needed anywhere).
__global__ void __launch_bounds__(256) k_tc(const u32* __restrict__ akey,
                                            u32* __restrict__ ccnt,
                                            u64* __restrict__ cand,
                                            u32* __restrict__ maxcU) {
    __shared__ u32 hist[NBIN];          // 32 KB
    __shared__ u32 seg[128];
    __shared__ u32 Ts, cnt;
    int b = blockIdx.x, t = threadIdx.x;
    for (int i = t; i < NBIN; i += 256) hist[i] = 0;
    if (t == 0) cnt = 0;
    __syncthreads();
    const u32* ak = akey + b * NANCH;
    for (int i = t; i < NANCH; i += 256) atomicAdd(&hist[ak[i] >> 19], 1u);
    __syncthreads();
    if (t < 128) {
        u32 s = 0;
        for (int j = 0; j < 64; ++j) s += hist[t * 64 + j];
        seg[t] = s;
    }
    __syncthreads();
    if (t == 0) {
        u32 acc = 0;
        int Tv = 0;
        for (int g = 127; g >= 0; --g) {
            if (acc + seg[g] >= NTOP) {
                for (int bin = g * 64 + 63; bin >= g * 64; --bin) {
                    acc += hist[bin];
                    if (acc >= NTOP) { Tv = bin; break; }
                }
                break;
            }
            acc += seg[g];
        }
        Ts = (u32)Tv;
        maxcU[b] = 0;
    }
    __syncthreads();
    u32 T = Ts;
    for (int i = t; i < NANCH; i += 256) {
        u32 k = ak[i];
        if ((k >> 19) >= T) {
            u32 p = atomicAdd(&cnt, 1u);
            cand[b * NANCH + p] = ((u64)k << 32) | (u64)(0xFFFFFFFFu - (u32)i);
        }
    }
    __syncthreads();
    if (t == 0) ccnt[b] = cnt;
}

// ---------------------------------------------------------------- kernel D
__global__ void k_rank(const u64* __restrict__ cand, const u32* __restrict__ ccnt,
                       const int* __restrict__ aclass, const float* __restrict__ abox,
                       float* __restrict__ tscore, int* __restrict__ tclass,
                       float* __restrict__ tbox, u32* __restrict__ maxcU) {
    __shared__ u64 tile[1024];
    int b = blockIdx.y, tid = threadIdx.x;
    int C = (int)ccnt[b];
    const u64* ck = cand + b * NANCH;
    for (int base = blockIdx.x * 256; base < C; base += gridDim.x * 256) {
        int i = base + tid;
        bool have = i < C;
        u64 my = have ? ck[i] : 0ull;
        int rank = 0;
        for (int t0 = 0; t0 < C; t0 += 1024) {
            int nt = min(1024, C - t0);
            __syncthreads();
            for (int j = tid; j < nt; j += 256) tile[j] = ck[t0 + j];
            __syncthreads();
            if (have)
                for (int j = 0; j < nt; ++j) rank += (tile[j] > my) ? 1 : 0;
        }
        u32 mymax = 0;  // identity under monotone map
        if (have && rank < NTOP) {
            u32 a = 0xFFFFFFFFu - (u32)(my & 0xFFFFFFFFull);
            int src = b * NANCH + (int)a;
            int dst = b * NTOP + rank;
            float logit = funmap((u32)(my >> 32));
            float sc = 1.0f / (1.0f + expf(-logit));
            float b0 = abox[src * 4 + 0], b1 = abox[src * 4 + 1];
            float b2 = abox[src * 4 + 2], b3 = abox[src * 4 + 3];
            tscore[dst] = sc;
            tclass[dst] = aclass[src];
            tbox[dst * 4 + 0] = b0;
            tbox[dst * 4 + 1] = b1;
            tbox[dst * 4 + 2] = b2;
            tbox[dst * 4 + 3] = b3;
            if (sc >= 0.05f)
                mymax = fmap(fmaxf(fmaxf(b0, b1), fmaxf(b2, b3)));
        }
        for (int off = 32; off > 0; off >>= 1) {
            u32 o = (u32)__shfl_down((int)mymax, off);
            mymax = mymax > o ? mymax : o;
        }
        if ((tid & 63) == 0) atomicMax(&maxcU[b], mymax);
    }
}

// ---------------------------------------------------------------- kernel F
// upper-triangle tiles only (136 of 256)
__global__ void k_sup(const float* __restrict__ tbox, const int* __restrict__ tclass,
                      const u32* __restrict__ maxcU, u64* __restrict__ sup) {
    int u = blockIdx.x, b = blockIdx.y;
    int ti = 0, rem = u;
    while (rem >= NWORD - ti) { rem -= NWORD - ti; ++ti; }
    int tj = ti + rem;
    int t = threadIdx.x;
    __shared__ double jx1[64], jy1[64], jx2[64], jy2[64], jcx[64], jcy[64], jar[64];
    double mc1 = (double)funmap(maxcU[b]) + 1.0;
    int j = tj * 64 + t;
    if (j < NTOP) {
        const float* bx = tbox + (size_t)(b * NTOP + j) * 4;
        double o = (double)tclass[b * NTOP + j] * mc1;
        double x1 = (double)bx[0] + o, y1 = (double)bx[1] + o;
        double x2 = (double)bx[2] + o, y2 = (double)bx[3] + o;
        jx1[t] = x1; jy1[t] = y1; jx2[t] = x2; jy2[t] = y2;
        jcx[t] = (x1 + x2) * 0.5; jcy[t] = (y1 + y2) * 0.5;
        jar[t] = (x2 - x1 + 1.0) * (y2 - y1 + 1.0);
    }
    __syncthreads();
    int i = ti * 64 + t;
    if (i >= NTOP) return;
    const float* bx = tbox + (size_t)(b * NTOP + i) * 4;
    double o = (double)tclass[b * NTOP + i] * mc1;
    double ix1 = (double)bx[0] + o, iy1 = (double)bx[1] + o;
    double ix2 = (double)bx[2] + o, iy2 = (double)bx[3] + o;
    double icx = (ix1 + ix2) * 0.5, icy = (iy1 + iy2) * 0.5;
    double iar = (ix2 - ix1 + 1.0) * (iy2 - iy1 + 1.0);
    u64 bits = 0;
    int jbase = tj * 64;
    for (int jj = 0; jj < 64; ++jj) {
        int jg = jbase + jj;
        if (jg >= NTOP) break;
        if (jg <= i) continue;
        double xm = fmax(ix1, jx1[jj]), ym = fmax(iy1, jy1[jj]);
        double xM = fmin(ix2, jx2[jj]), yM = fmin(iy2, jy2[jj]);
        double inter = fmax(xM - xm, 0.0) * fmax(yM - ym, 0.0);
        double iou = inter / (iar + jar[jj] - inter);
        double dx = icx - jcx[jj], dy = icy - jcy[jj];
        double idg = dx * dx + dy * dy;
        double ox = fmax(ix2, jx2[jj]) - fmin(ix1, jx1[jj]);
        double oy = fmax(iy2, jy2[jj]) - fmin(iy1, jy1[jj]);
        double odg = ox * ox + oy * oy;
        double diou = iou - idg / fmax(odg, 1e-12);
        if (diou > 0.6) bits |= (1ull << jj);
    }
    sup[(size_t)(b * NTOP + i) * NWORD + tj] = bits;
}

// ---------------------------------------------------------------- kernel G
// Wave-synchronous scan: lane w holds cross-tile removed word w (2 VGPRs,
// no register arrays -> no scratch). Per tile: stage 8KB to LDS (padded),
// ffs loop over KEPT rows only (one u64 shuffle each), fold kept rows into
// distributed removed words. Early-exit at 100 kept.
__global__ void __launch_bounds__(64) k_scan(
        const u64* __restrict__ sup, const float* __restrict__ tscore,
        const int* __restrict__ tclass, const float* __restrict__ tbox,
        float* __restrict__ out) {
    int b = blockIdx.x, lane = threadIdx.x;  // one wave
    __shared__ u64 lds[64 * 17];             // padded tile (8.5 KB)
    __shared__ int kept_lds[NOUT];
    const u64* supb = sup + (size_t)b * NTOP * NWORD;
    u64 remw = 0;                            // lane w<16: removed word w
    int kept = 0;
    for (int t = 0; t < NWORD; ++t) {
        int r0 = t * 64;
        // stage tile rows r0..r0+63 (words 0..15) into padded LDS
#pragma unroll
        for (int q = 0; q < 16; ++q) {
            int e = q * 64 + lane;
            int rr = r0 + (e >> 4), w = e & 15;
            u64 v = (rr < NTOP) ? supb[(size_t)rr * 16 + w] : 0ull;
            lds[(e >> 4) * 17 + w] = v;
        }
        __syncthreads();
        int r = r0 + lane;
        float s = (r < NTOP) ? tscore[b * NTOP + r] : -1.0f;
        u64 vmask = __ballot(s >= 0.05f);
        u64 M = lds[lane * 17 + t];          // in-tile word for this lane's row
        u64 rem_t = __shfl(remw, t);         // cross-tile removed bits, word t
        u64 cand = vmask & ~rem_t;
        u64 keepmask = 0;
        while (cand) {
            int k = __ffsll(cand) - 1;
            keepmask |= 1ull << k;
            if (lane == 0) kept_lds[kept] = r0 + k;
            ++kept;
            if (kept >= NOUT) break;
            u64 Mk = __shfl(M, k);
            cand &= ~(Mk | (1ull << k));
        }
        // fold kept rows into distributed removed words (lanes 0..15)
        if (lane < NWORD) {
            u64 km = keepmask;
            while (km) {
                int k = __ffsll(km) - 1;
                km &= km - 1;
                remw |= lds[k * 17 + lane];
            }
        }
        __syncthreads();
        if (kept >= NOUT) break;
    }
    float* os = out + b * NOUT;
    float* oc = out + BB * NOUT + b * NOUT;
    float* ob = out + 2 * BB * NOUT + (size_t)b * NOUT * 4;
    for (int i = lane; i < NOUT; i += 64) { os[i] = -2.0f; oc[i] = -2.0f; }
    for (int i = lane; i < NOUT * 4; i += 64) ob[i] = -2.0f;
    __syncthreads();
    int ncopy = kept < NOUT ? kept : NOUT;
    for (int r = lane; r < ncopy; r += 64) {
        int i = kept_lds[r];
        os[r] = tscore[b * NTOP + i];
        oc[r] = (float)tclass[b * NTOP + i];
        ob[r * 4 + 0] = tbox[(size_t)(b * NTOP + i) * 4 + 0];
        ob[r * 4 + 1] = tbox[(size_t)(b * NTOP + i) * 4 + 1];
        ob[r * 4 + 2] = tbox[(size_t)(b * NTOP + i) * 4 + 2];
        ob[r * 4 + 3] = tbox[(size_t)(b * NTOP + i) * 4 + 3];
    }
}

// ---------------------------------------------------------------- launch
extern "C" void kernel_launch(void* const* d_in, const int* in_sizes, int n_in,
                              void* d_out, int out_size, void* d_ws, size_t ws_size,
                              hipStream_t stream) {
    (void)in_sizes; (void)n_in; (void)out_size; (void)ws_size;
    const float* cls[5];
    const float* reg[5];
    for (int i = 0; i < 5; ++i) {
        cls[i] = (const float*)d_in[2 * i];
        reg[i] = (const float*)d_in[2 * i + 1];
    }
    float* out = (float*)d_out;

    char* ws = (char*)d_ws;
    u64* cand = (u64*)ws;            ws += (size_t)BB * NANCH * sizeof(u64);
    u64* sup = (u64*)ws;             ws += (size_t)BB * NTOP * NWORD * sizeof(u64);
    u32* akey = (u32*)ws;            ws += (size_t)BB * NANCH * sizeof(u32);
    int* aclass = (int*)ws;          ws += (size_t)BB * NANCH * sizeof(int);
    float* abox = (float*)ws;        ws += (size_t)BB * NANCH * 4 * sizeof(float);
    float* tscore = (float*)ws;      ws += (size_t)BB * NTOP * sizeof(float);
    int* tclass = (int*)ws;          ws += (size_t)BB * NTOP * sizeof(int);
    float* tbox = (float*)ws;        ws += (size_t)BB * NTOP * 4 * sizeof(float);
    u32* ccnt = (u32*)ws;            ws += 64;
    u32* maxcU = (u32*)ws;           ws += 64;

    k_anchor<<<dim3((4 * NGRP + 255) / 256, BB), 256, 0, stream>>>(
        cls[0], cls[1], cls[2], cls[3], cls[4],
        reg[0], reg[1], reg[2], reg[3], reg[4],
        akey, aclass, abox);
    k_tc<<<BB, 256, 0, stream>>>(akey, ccnt, cand, maxcU);
    k_rank<<<dim3(32, BB), 256, 0, stream>>>(cand, ccnt, aclass, abox,
                                             tscore, tclass, tbox, maxcU);
    k_sup<<<dim3(136, BB), 64, 0, stream>>>(tbox, tclass, maxcU, sup);
    k_scan<<<BB, 64, 0, stream>>>(sup, tscore, tclass, tbox, out);
}

// Round 6
// 272.999 us; speedup vs baseline: 1.8339x; 1.0930x over previous
//
#include <hip/hip_runtime.h>
#include <math.h>

typedef unsigned int u32;
typedef unsigned long long u64;

#define BB 16
#define NANCH 17064
#define NGRP 4266          // NANCH / 4
#define NTOP 1000
#define NWORD 16
#define NOUT 100
#define NBIN 8192

__device__ __forceinline__ u32 fmap(float v) {
    u32 u = __float_as_uint(v);
    return (u & 0x80000000u) ? ~u : (u | 0x80000000u);
}
__device__ __forceinline__ float funmap(u32 u) {
    u32 b = (u & 0x80000000u) ? (u & 0x7FFFFFFFu) : ~u;
    return __uint_as_float(b);
}

// ---------------------------------------------------------------- kernel A
// Pure streaming: 4 threads per 4-anchor group (20 classes each), float4
// loads, two-stage shfl_xor combine (lower class-quarter wins ties ==
// first-max argmax). No LDS, no atomics.
__global__ void __launch_bounds__(256) k_anchor(
        const float* __restrict__ c0, const float* __restrict__ c1,
        const float* __restrict__ c2, const float* __restrict__ c3,
        const float* __restrict__ c4,
        const float* __restrict__ r0, const float* __restrict__ r1,
        const float* __restrict__ r2, const float* __restrict__ r3,
        const float* __restrict__ r4,
        u32* __restrict__ akey, int* __restrict__ aclass,
        float* __restrict__ abox) {
    int tid = threadIdx.x;
    int b = blockIdx.y;
    int gt = blockIdx.x * 256 + tid;         // 4 * NGRP = 17064 used
    if (gt >= 4 * NGRP) return;
    int p = gt >> 2, cs = gt & 3;            // group, class-quarter
    int a = p * 4;

    const float *cp, *rp;
    int loc, wl, h, stride, half;
    if (a < 12800)      { loc = a;         wl = 7; h = 100; stride = 8;   half = 4;  cp = c0; rp = r0; }
    else if (a < 16000) { loc = a - 12800; wl = 6; h = 50;  stride = 16;  half = 8;  cp = c1; rp = r1; }
    else if (a < 16800) { loc = a - 16000; wl = 5; h = 25;  stride = 32;  half = 16; cp = c2; rp = r2; }
    else if (a < 17008) { loc = a - 16800; wl = 4; h = 13;  stride = 64;  half = 32; cp = c3; rp = r3; }
    else                { loc = a - 17008; wl = 3; h = 7;   stride = 128; half = 64; cp = c4; rp = r4; }
    int y = loc >> wl, x = loc & ((1 << wl) - 1);
    int hw = h << wl, hwq = hw >> 2;

    const float4* cb4 = (const float4*)(cp + (size_t)b * 80 * hw +
                                        (size_t)cs * 20 * hw + loc);
    int cbase = cs * 20;
    float4 v = cb4[0];
    float m0 = v.x, m1 = v.y, m2 = v.z, m3 = v.w;
    int a0 = cbase, a1 = cbase, a2 = cbase, a3 = cbase;
#pragma unroll
    for (int c = 1; c < 20; ++c) {
        float4 u = cb4[(size_t)c * hwq];
        int cc = cbase + c;
        if (u.x > m0) { m0 = u.x; a0 = cc; }
        if (u.y > m1) { m1 = u.y; a1 = cc; }
        if (u.z > m2) { m2 = u.z; a2 = cc; }
        if (u.w > m3) { m3 = u.w; a3 = cc; }
    }
    // stage 1: xor-1 partner; lower class-quarter wins ties
    {
        bool low = (cs & 1) == 0;
        float pm; int pa; bool tk;
        pm = __shfl_xor(m0, 1); pa = __shfl_xor(a0, 1);
        tk = low ? (m0 >= pm) : (m0 > pm); m0 = tk ? m0 : pm; a0 = tk ? a0 : pa;
        pm = __shfl_xor(m1, 1); pa = __shfl_xor(a1, 1);
        tk = low ? (m1 >= pm) : (m1 > pm); m1 = tk ? m1 : pm; a1 = tk ? a1 : pa;
        pm = __shfl_xor(m2, 1); pa = __shfl_xor(a2, 1);
        tk = low ? (m2 >= pm) : (m2 > pm); m2 = tk ? m2 : pm; a2 = tk ? a2 : pa;
        pm = __shfl_xor(m3, 1); pa = __shfl_xor(a3, 1);
        tk = low ? (m3 >= pm) : (m3 > pm); m3 = tk ? m3 : pm; a3 = tk ? a3 : pa;
    }
    // stage 2: xor-2 partner; lower half wins ties
    {
        bool low = (cs & 2) == 0;
        float pm; int pa; bool tk;
        pm = __shfl_xor(m0, 2); pa = __shfl_xor(a0, 2);
        tk = low ? (m0 >= pm) : (m0 > pm); m0 = tk ? m0 : pm; a0 = tk ? a0 : pa;
        pm = __shfl_xor(m1, 2); pa = __shfl_xor(a1, 2);
        tk = low ? (m1 >= pm) : (m1 > pm); m1 = tk ? m1 : pm; a1 = tk ? a1 : pa;
        pm = __shfl_xor(m2, 2); pa = __shfl_xor(a2, 2);
        tk = low ? (m2 >= pm) : (m2 > pm); m2 = tk ? m2 : pm; a2 = tk ? a2 : pa;
        pm = __shfl_xor(m3, 2); pa = __shfl_xor(a3, 2);
        tk = low ? (m3 >= pm) : (m3 > pm); m3 = tk ? m3 : pm; a3 = tk ? a3 : pa;
    }
    if (cs == 0) {
        const float4* rb4 = (const float4*)(rp + (size_t)b * 4 * hw + loc);
        float4 gl = rb4[0], gt_ = rb4[hwq], gr = rb4[2 * hwq], gb = rb4[3 * hwq];

        int idx = b * NANCH + a;
        *(uint4*)(akey + idx) = make_uint4(fmap(m0), fmap(m1), fmap(m2), fmap(m3));
        *(int4*)(aclass + idx) = make_int4(a0 + 1, a1 + 1, a2 + 1, a3 + 1);
        float cy = (float)(y * stride + half);
        float cx0 = (float)(x * stride + half);
        float gls[4] = {gl.x, gl.y, gl.z, gl.w};
        float gts[4] = {gt_.x, gt_.y, gt_.z, gt_.w};
        float grs[4] = {gr.x, gr.y, gr.z, gr.w};
        float gbs[4] = {gb.x, gb.y, gb.z, gb.w};
#pragma unroll
        for (int k = 0; k < 4; ++k) {
            float cx = cx0 + (float)(k * stride);
            *(float4*)(abox + (size_t)(idx + k) * 4) =
                make_float4(cx - gls[k], cy - gts[k], cx + grs[k], cy + gbs[k]);
        }
    }
}

// ---------------------------------------------------------------- kernel B
// fused per-batch: 13-bit histogram -> bin T -> REFINE with key bits 6..18
// within bin T -> 26-bit-prefix threshold -> compact candidates (C ~ 1000).
__global__ void __launch_bounds__(256) k_tc(const u32* __restrict__ akey,
                                            u32* __restrict__ ccnt,
                                            u64* __restrict__ cand,
                                            u32* __restrict__ maxcU) {
    __shared__ u32 hist[NBIN];          // 32 KB (reused for both passes)
    __shared__ u32 seg[128];
    __shared__ u32 Ts, T2s, cnt;
    int b = blockIdx.x, t = threadIdx.x;
    const u32* ak = akey + b * NANCH;

    // ---- pass 1: 13-bit bins (key >> 19) ----
    for (int i = t; i < NBIN; i += 256) hist[i] = 0;
    if (t == 0) cnt = 0;
    __syncthreads();
    for (int i = t; i < NANCH; i += 256) atomicAdd(&hist[ak[i] >> 19], 1u);
    __syncthreads();
    if (t < 128) {
        u32 s = 0;
        for (int j = 0; j < 64; ++j) s += hist[t * 64 + j];
        seg[t] = s;
    }
    __syncthreads();
    __shared__ u32 nAboveS;
    if (t == 0) {
        u32 acc = 0;
        int Tv = 0;
        u32 nAbove = 0;
        for (int g = 127; g >= 0; --g) {
            if (acc + seg[g] >= NTOP) {
                for (int bin = g * 64 + 63; bin >= g * 64; --bin) {
                    u32 h = hist[bin];
                    if (acc + h >= NTOP) { Tv = bin; nAbove = acc; break; }
                    acc += h;
                }
                break;
            }
            acc += seg[g];
        }
        Ts = (u32)Tv;
        nAboveS = nAbove;           // count of keys strictly above bin T
        maxcU[b] = 0;
    }
    __syncthreads();
    u32 T = Ts;
    u32 need = NTOP - nAboveS;      // how many we need from bin T

    // ---- pass 2: refine within bin T using key bits 6..18 ----
    for (int i = t; i < NBIN; i += 256) hist[i] = 0;
    __syncthreads();
    for (int i = t; i < NANCH; i += 256) {
        u32 k = ak[i];
        if ((k >> 19) == T) atomicAdd(&hist[(k >> 6) & 8191u], 1u);
    }
    __syncthreads();
    if (t < 128) {
        u32 s = 0;
        for (int j = 0; j < 64; ++j) s += hist[t * 64 + j];
        seg[t] = s;
    }
    __syncthreads();
    if (t == 0) {
        u32 acc = 0;
        int Tv = 0;
        for (int g = 127; g >= 0; --g) {
            if (acc + seg[g] >= need) {
                for (int bin = g * 64 + 63; bin >= g * 64; --bin) {
                    acc += hist[bin];
                    if (acc >= need) { Tv = bin; break; }
                }
                break;
            }
            acc += seg[g];
        }
        T2s = (u32)Tv;
    }
    __syncthreads();
    u32 T2 = T2s;

    // ---- compact: 26-bit prefix >= (T:T2) ----
    for (int i = t; i < NANCH; i += 256) {
        u32 k = ak[i];
        u32 hi = k >> 19;
        if (hi > T || (hi == T && ((k >> 6) & 8191u) >= T2)) {
            u32 p = atomicAdd(&cnt, 1u);
            cand[b * NANCH + p] = ((u64)k << 32) | (u64)(0xFFFFFFFFu - (u32)i);
        }
    }
    __syncthreads();
    if (t == 0) ccnt[b] = cnt;
}

// ---------------------------------------------------------------- kernel D
// exact rank among ~1000 candidates; 8-way-unrolled LDS scan (independent
// accumulators -> ds_read_b128 batches, latency hidden).
__global__ void __launch_bounds__(256) k_rank(
        const u64* __restrict__ cand, const u32* __restrict__ ccnt,
        const int* __restrict__ aclass, const float* __restrict__ abox,
        float* __restrict__ tscore, int* __restrict__ tclass,
        float* __restrict__ tbox, u32* __restrict__ maxcU) {
    __shared__ u64 tile[2048];          // 16 KB
    int b = blockIdx.y, tid = threadIdx.x;
    int C = (int)ccnt[b];
    const u64* ck = cand + b * NANCH;
    for (int base = blockIdx.x * 256; base < C; base += gridDim.x * 256) {
        int i = base + tid;
        bool have = i < C;
        u64 my = have ? ck[i] : 0ull;
        int rank = 0;
        for (int t0 = 0; t0 < C; t0 += 2048) {
            int nt = min(2048, C - t0);
            __syncthreads();
            for (int j = tid; j < nt; j += 256) tile[j] = ck[t0 + j];
            __syncthreads();
            int r0 = 0, r1 = 0, r2 = 0, r3 = 0, r4 = 0, r5 = 0, r6 = 0, r7 = 0;
            int j = 0;
            for (; j + 8 <= nt; j += 8) {
                u64 v0 = tile[j + 0], v1 = tile[j + 1];
                u64 v2 = tile[j + 2], v3 = tile[j + 3];
                u64 v4 = tile[j + 4], v5 = tile[j + 5];
                u64 v6 = tile[j + 6], v7 = tile[j + 7];
                r0 += v0 > my; r1 += v1 > my; r2 += v2 > my; r3 += v3 > my;
                r4 += v4 > my; r5 += v5 > my; r6 += v6 > my; r7 += v7 > my;
            }
            for (; j < nt; ++j) r0 += tile[j] > my;
            rank += ((r0 + r1) + (r2 + r3)) + ((r4 + r5) + (r6 + r7));
        }
        u32 mymax = 0;  // identity under monotone map
        if (have && rank < NTOP) {
            u32 a = 0xFFFFFFFFu - (u32)(my & 0xFFFFFFFFull);
            int src = b * NANCH + (int)a;
            int dst = b * NTOP + rank;
            float logit = funmap((u32)(my >> 32));
            float sc = 1.0f / (1.0f + expf(-logit));
            float b0 = abox[src * 4 + 0], b1 = abox[src * 4 + 1];
            float b2 = abox[src * 4 + 2], b3 = abox[src * 4 + 3];
            tscore[dst] = sc;
            tclass[dst] = aclass[src];
            tbox[dst * 4 + 0] = b0;
            tbox[dst * 4 + 1] = b1;
            tbox[dst * 4 + 2] = b2;
            tbox[dst * 4 + 3] = b3;
            if (sc >= 0.05f)
                mymax = fmap(fmaxf(fmaxf(b0, b1), fmaxf(b2, b3)));
        }
        for (int off = 32; off > 0; off >>= 1) {
            u32 o = (u32)__shfl_down((int)mymax, off);
            mymax = mymax > o ? mymax : o;
        }
        if ((tid & 63) == 0) atomicMax(&maxcU[b], mymax);
    }
}

// ---------------------------------------------------------------- kernel F
// upper-triangle tiles only (136 of 256)
__global__ void k_sup(const float* __restrict__ tbox, const int* __restrict__ tclass,
                      const u32* __restrict__ maxcU, u64* __restrict__ sup) {
    int u = blockIdx.x, b = blockIdx.y;
    int ti = 0, rem = u;
    while (rem >= NWORD - ti) { rem -= NWORD - ti; ++ti; }
    int tj = ti + rem;
    int t = threadIdx.x;
    __shared__ double jx1[64], jy1[64], jx2[64], jy2[64], jcx[64], jcy[64], jar[64];
    double mc1 = (double)funmap(maxcU[b]) + 1.0;
    int j = tj * 64 + t;
    if (j < NTOP) {
        const float* bx = tbox + (size_t)(b * NTOP + j) * 4;
        double o = (double)tclass[b * NTOP + j] * mc1;
        double x1 = (double)bx[0] + o, y1 = (double)bx[1] + o;
        double x2 = (double)bx[2] + o, y2 = (double)bx[3] + o;
        jx1[t] = x1; jy1[t] = y1; jx2[t] = x2; jy2[t] = y2;
        jcx[t] = (x1 + x2) * 0.5; jcy[t] = (y1 + y2) * 0.5;
        jar[t] = (x2 - x1 + 1.0) * (y2 - y1 + 1.0);
    }
    __syncthreads();
    int i = ti * 64 + t;
    if (i >= NTOP) return;
    const float* bx = tbox + (size_t)(b * NTOP + i) * 4;
    double o = (double)tclass[b * NTOP + i] * mc1;
    double ix1 = (double)bx[0] + o, iy1 = (double)bx[1] + o;
    double ix2 = (double)bx[2] + o, iy2 = (double)bx[3] + o;
    double icx = (ix1 + ix2) * 0.5, icy = (iy1 + iy2) * 0.5;
    double iar = (ix2 - ix1 + 1.0) * (iy2 - iy1 + 1.0);
    u64 bits = 0;
    int jbase = tj * 64;
    for (int jj = 0; jj < 64; ++jj) {
        int jg = jbase + jj;
        if (jg >= NTOP) break;
        if (jg <= i) continue;
        double xm = fmax(ix1, jx1[jj]), ym = fmax(iy1, jy1[jj]);
        double xM = fmin(ix2, jx2[jj]), yM = fmin(iy2, jy2[jj]);
        double inter = fmax(xM - xm, 0.0) * fmax(yM - ym, 0.0);
        double iou = inter / (iar + jar[jj] - inter);
        double dx = icx - jcx[jj], dy = icy - jcy[jj];
        double idg = dx * dx + dy * dy;
        double ox = fmax(ix2, jx2[jj]) - fmin(ix1, jx1[jj]);
        double oy = fmax(iy2, jy2[jj]) - fmin(iy1, jy1[jj]);
        double odg = ox * ox + oy * oy;
        double diou = iou - idg / fmax(odg, 1e-12);
        if (diou > 0.6) bits |= (1ull << jj);
    }
    sup[(size_t)(b * NTOP + i) * NWORD + tj] = bits;
}

// ---------------------------------------------------------------- kernel G
// Wave-synchronous scan: lane w holds cross-tile removed word w. Per tile:
// stage 8KB to LDS (padded), ffs loop over KEPT rows only, fold kept rows
// into distributed removed words. Early-exit at 100 kept.
__global__ void __launch_bounds__(64) k_scan(
        const u64* __restrict__ sup, const float* __restrict__ tscore,
        const int* __restrict__ tclass, const float* __restrict__ tbox,
        float* __restrict__ out) {
    int b = blockIdx.x, lane = threadIdx.x;  // one wave
    __shared__ u64 lds[64 * 17];             // padded tile (8.5 KB)
    __shared__ int kept_lds[NOUT];
    const u64* supb = sup + (size_t)b * NTOP * NWORD;
    u64 remw = 0;                            // lane w<16: removed word w
    int kept = 0;
    for (int t = 0; t < NWORD; ++t) {
        int r0 = t * 64;
#pragma unroll
        for (int q = 0; q < 16; ++q) {
            int e = q * 64 + lane;
            int rr = r0 + (e >> 4), w = e & 15;
            u64 v = (rr < NTOP) ? supb[(size_t)rr * 16 + w] : 0ull;
            lds[(e >> 4) * 17 + w] = v;
        }
        __syncthreads();
        int r = r0 + lane;
        float s = (r < NTOP) ? tscore[b * NTOP + r] : -1.0f;
        u64 vmask = __ballot(s >= 0.05f);
        u64 M = lds[lane * 17 + t];          // in-tile word for this lane's row
        u64 rem_t = __shfl(remw, t);         // cross-tile removed bits, word t
        u64 cand = vmask & ~rem_t;
        u64 keepmask = 0;
        while (cand) {
            int k = __ffsll(cand) - 1;
            keepmask |= 1ull << k;
            if (lane == 0) kept_lds[kept] = r0 + k;
            ++kept;
            if (kept >= NOUT) break;
            u64 Mk = __shfl(M, k);
            cand &= ~(Mk | (1ull << k));
        }
        if (lane < NWORD) {
            u64 km = keepmask;
            while (km) {
                int k = __ffsll(km) - 1;
                km &= km - 1;
                remw |= lds[k * 17 + lane];
            }
        }
        __syncthreads();
        if (kept >= NOUT) break;
    }
    float* os = out + b * NOUT;
    float* oc = out + BB * NOUT + b * NOUT;
    float* ob = out + 2 * BB * NOUT + (size_t)b * NOUT * 4;
    for (int i = lane; i < NOUT; i += 64) { os[i] = -2.0f; oc[i] = -2.0f; }
    for (int i = lane; i < NOUT * 4; i += 64) ob[i] = -2.0f;
    __syncthreads();
    int ncopy = kept < NOUT ? kept : NOUT;
    for (int r = lane; r < ncopy; r += 64) {
        int i = kept_lds[r];
        os[r] = tscore[b * NTOP + i];
        oc[r] = (float)tclass[b * NTOP + i];
        ob[r * 4 + 0] = tbox[(size_t)(b * NTOP + i) * 4 + 0];
        ob[r * 4 + 1] = tbox[(size_t)(b * NTOP + i) * 4 + 1];
        ob[r * 4 + 2] = tbox[(size_t)(b * NTOP + i) * 4 + 2];
        ob[r * 4 + 3] = tbox[(size_t)(b * NTOP + i) * 4 + 3];
    }
}

// ---------------------------------------------------------------- launch
extern "C" void kernel_launch(void* const* d_in, const int* in_sizes, int n_in,
                              void* d_out, int out_size, void* d_ws, size_t ws_size,
                              hipStream_t stream) {
    (void)in_sizes; (void)n_in; (void)out_size; (void)ws_size;
    const float* cls[5];
    const float* reg[5];
    for (int i = 0; i < 5; ++i) {
        cls[i] = (const float*)d_in[2 * i];
        reg[i] = (const float*)d_in[2 * i + 1];
    }
    float* out = (float*)d_out;

    char* ws = (char*)d_ws;
    u64* cand = (u64*)ws;            ws += (size_t)BB * NANCH * sizeof(u64);
    u64* sup = (u64*)ws;             ws += (size_t)BB * NTOP * NWORD * sizeof(u64);
    u32* akey = (u32*)ws;            ws += (size_t)BB * NANCH * sizeof(u32);
    int* aclass = (int*)ws;          ws += (size_t)BB * NANCH * sizeof(int);
    float* abox = (float*)ws;        ws += (size_t)BB * NANCH * 4 * sizeof(float);
    float* tscore = (float*)ws;      ws += (size_t)BB * NTOP * sizeof(float);
    int* tclass = (int*)ws;          ws += (size_t)BB * NTOP * sizeof(int);
    float* tbox = (float*)ws;        ws += (size_t)BB * NTOP * 4 * sizeof(float);
    u32* ccnt = (u32*)ws;            ws += 64;
    u32* maxcU = (u32*)ws;           ws += 64;

    k_anchor<<<dim3((4 * NGRP + 255) / 256, BB), 256, 0, stream>>>(
        cls[0], cls[1], cls[2], cls[3], cls[4],
        reg[0], reg[1], reg[2], reg[3], reg[4],
        akey, aclass, abox);
    k_tc<<<BB, 256, 0, stream>>>(akey, ccnt, cand, maxcU);
    k_rank<<<dim3(8, BB), 256, 0, stream>>>(cand, ccnt, aclass, abox,
                                            tscore, tclass, tbox, maxcU);
    k_sup<<<dim3(136, BB), 64, 0, stream>>>(tbox, tclass, maxcU, sup);
    k_scan<<<BB, 64, 0, stream>>>(sup, tscore, tclass, tbox, out);
}